// Round 1
// baseline (1616.012 us; speedup 1.0000x reference)
//
#include <hip/hip_runtime.h>
#include <math.h>

#define SEQL 197
#define HD 768
#define NH 12
#define DHD 64
#define BATCH 64
#define OUTD 1000

// ---------------- positional embedding table ----------------
__global__ void k_pos(float* __restrict__ pos) {
    int i = blockIdx.x * 256 + threadIdx.x;
    if (i >= SEQL * HD) return;
    int s = i / HD, d = i % HD;
    float f = (float)(d & ~1);
    float r = powf(10000.0f, -f / (float)HD);
    float a = (float)s * r;
    pos[i] = (d & 1) ? cosf(a) : sinf(a);
}

// ---------------- cls row of tokens ----------------
__global__ void k_cls(const float* __restrict__ cls_tok, const float* __restrict__ pos,
                      float* __restrict__ tok) {
    int i = blockIdx.x * 256 + threadIdx.x;
    if (i >= BATCH * HD) return;
    int b = i / HD, e = i % HD;
    tok[(b * SEQL) * HD + e] = cls_tok[e] + pos[e];
}

// ---------------- patch embed GEMM: tokens[s>=1] = patches @ W_map + b_map + pos ----
// M = 64*196 = 12544 (exact 98*128), N = 768 (6*128), K = 768
__launch_bounds__(256)
__global__ void k_embed(const float* __restrict__ img, const float* __restrict__ Wm,
                        const float* __restrict__ bm, const float* __restrict__ pos,
                        float* __restrict__ tok) {
    __shared__ float As[16][132];
    __shared__ float Bs[16][132];
    const int m0 = blockIdx.x * 128;
    const int n0 = blockIdx.y * 128;
    const int tid = threadIdx.x;
    const int tx = tid & 15, ty = tid >> 4;

    float acc[8][8];
#pragma unroll
    for (int i = 0; i < 8; ++i)
#pragma unroll
        for (int j = 0; j < 8; ++j) acc[i][j] = 0.f;

    for (int k0 = 0; k0 < 768; k0 += 16) {
        // stage A: gather from images. k = c*256 + ir*16 + j ; 16 k's contiguous.
        const int c = k0 >> 8;
        const int ir = (k0 & 255) >> 4;
#pragma unroll
        for (int l = 0; l < 2; ++l) {
            int ii = tid + l * 256;            // 0..511
            int row = ii >> 2, kq = ii & 3;
            int m = m0 + row;
            int b = m / 196, pi = m % 196;
            int pr = pi / 14, pc = pi % 14;
            const float4 av = *(const float4*)&img[((b * 3 + c) * 224 + pr * 16 + ir) * 224 + pc * 16 + kq * 4];
            As[kq * 4 + 0][row] = av.x;
            As[kq * 4 + 1][row] = av.y;
            As[kq * 4 + 2][row] = av.z;
            As[kq * 4 + 3][row] = av.w;
        }
        // stage B
#pragma unroll
        for (int l = 0; l < 2; ++l) {
            int ii = tid + l * 256;            // 0..511
            int kr = ii >> 5, nq = ii & 31;
            *(float4*)&Bs[kr][nq * 4] = *(const float4*)&Wm[(k0 + kr) * 768 + n0 + nq * 4];
        }
        __syncthreads();
#pragma unroll
        for (int kk = 0; kk < 16; ++kk) {
            float a[8], bv[8];
            *(float4*)&a[0] = *(float4*)&As[kk][ty * 8];
            *(float4*)&a[4] = *(float4*)&As[kk][ty * 8 + 4];
            *(float4*)&bv[0] = *(float4*)&Bs[kk][tx * 8];
            *(float4*)&bv[4] = *(float4*)&Bs[kk][tx * 8 + 4];
#pragma unroll
            for (int i = 0; i < 8; ++i)
#pragma unroll
                for (int j = 0; j < 8; ++j) acc[i][j] += a[i] * bv[j];
        }
        __syncthreads();
    }
    // epilogue: + b_map + pos, write tokens rows s>=1
#pragma unroll
    for (int i = 0; i < 8; ++i) {
        int m = m0 + ty * 8 + i;
        int b = m / 196, s = 1 + m % 196;
        float* dst = &tok[((b * SEQL) + s) * HD + n0 + tx * 8];
        const float* pp = &pos[s * HD + n0 + tx * 8];
        const float* bb = &bm[n0 + tx * 8];
#pragma unroll
        for (int jq = 0; jq < 2; ++jq) {
            float4 o;
            o.x = acc[i][jq * 4 + 0] + pp[jq * 4 + 0] + bb[jq * 4 + 0];
            o.y = acc[i][jq * 4 + 1] + pp[jq * 4 + 1] + bb[jq * 4 + 1];
            o.z = acc[i][jq * 4 + 2] + pp[jq * 4 + 2] + bb[jq * 4 + 2];
            o.w = acc[i][jq * 4 + 3] + pp[jq * 4 + 3] + bb[jq * 4 + 3];
            *(float4*)&dst[jq * 4] = o;
        }
    }
}

// ---------------- 2D LayerNorm stats (mean, rsigma) per image ----------------
__global__ void k_lnstats(const float* __restrict__ buf, float* __restrict__ stats, int which) {
    int b = blockIdx.x;
    const float* p = buf + (size_t)b * SEQL * HD;
    float s = 0.f, s2 = 0.f;
    const int NV = SEQL * HD / 4;   // 37824
    for (int i = threadIdx.x; i < NV; i += 256) {
        float4 v = ((const float4*)p)[i];
        s += v.x + v.y + v.z + v.w;
        s2 += v.x * v.x + v.y * v.y + v.z * v.z + v.w * v.w;
    }
    __shared__ float rs[8], rs2[8];
#pragma unroll
    for (int off = 32; off > 0; off >>= 1) {
        s += __shfl_down(s, off);
        s2 += __shfl_down(s2, off);
    }
    int lane = threadIdx.x & 63, w = threadIdx.x >> 6;
    if (lane == 0) { rs[w] = s; rs2[w] = s2; }
    __syncthreads();
    if (threadIdx.x == 0) {
        float S = 0.f, S2 = 0.f;
        for (int i = 0; i < 4; ++i) { S += rs[i]; S2 += rs2[i]; }
        const float inv_n = 1.0f / (float)(SEQL * HD);
        float mu = S * inv_n;
        float var = S2 * inv_n - mu * mu;
        stats[which * 128 + b * 2] = mu;
        stats[which * 128 + b * 2 + 1] = rsqrtf(var + 1e-5f);
    }
}

// ---------------- QKV projections (LN1 fused on load) ----------------
// block per (b,h); q/k/v layout: [(b*12+h)][s][e]
__launch_bounds__(256)
__global__ void k_qkv(const float* __restrict__ tok, const float* __restrict__ stats,
                      const float* __restrict__ g1, const float* __restrict__ b1,
                      const float* __restrict__ Wq, const float* __restrict__ bq,
                      const float* __restrict__ Wk, const float* __restrict__ bk,
                      const float* __restrict__ Wv, const float* __restrict__ bv,
                      float* __restrict__ q, float* __restrict__ k, float* __restrict__ v) {
    const int h = blockIdx.x % 12, b = blockIdx.x / 12;
    __shared__ float Ws[3][64][68];
    __shared__ float Xs[64][68];
    const int tid = threadIdx.x, tx = tid & 15, ty = tid >> 4;

#pragma unroll
    for (int l = 0; l < 12; ++l) {
        int ii = tid + l * 256;               // 0..3071
        int pj = ii >> 10, rem = ii & 1023;
        int d = rem >> 4, eq = rem & 15;
        const float* W = (pj == 0) ? Wq : (pj == 1) ? Wk : Wv;
        *(float4*)&Ws[pj][d][eq * 4] = *(const float4*)&W[(h * 64 + d) * 64 + eq * 4];
    }
    const float mu = stats[b * 2], rsg = stats[b * 2 + 1];
    const long base = (long)(b * 12 + h) * SEQL * 64;

    for (int st = 0; st < 4; ++st) {
        const int s0 = st * 64;
        __syncthreads();
#pragma unroll
        for (int l = 0; l < 4; ++l) {
            int ii = tid + l * 256;           // 0..1023
            int sl = ii >> 4, dq = ii & 15;
            int sg = s0 + sl;
            float4 xv = {0.f, 0.f, 0.f, 0.f};
            if (sg < SEQL) {
                float4 t4 = *(const float4*)&tok[(b * SEQL + sg) * HD + h * 64 + dq * 4];
                float4 g4 = *(const float4*)&g1[sg * HD + h * 64 + dq * 4];
                float4 bb4 = *(const float4*)&b1[sg * HD + h * 64 + dq * 4];
                xv.x = (t4.x - mu) * rsg * g4.x + bb4.x;
                xv.y = (t4.y - mu) * rsg * g4.y + bb4.y;
                xv.z = (t4.z - mu) * rsg * g4.z + bb4.z;
                xv.w = (t4.w - mu) * rsg * g4.w + bb4.w;
            }
            Xs[dq * 4 + 0][sl] = xv.x;
            Xs[dq * 4 + 1][sl] = xv.y;
            Xs[dq * 4 + 2][sl] = xv.z;
            Xs[dq * 4 + 3][sl] = xv.w;
        }
        __syncthreads();
#pragma unroll
        for (int pj = 0; pj < 3; ++pj) {
            float acc[4][4];
#pragma unroll
            for (int i = 0; i < 4; ++i)
#pragma unroll
                for (int j = 0; j < 4; ++j) acc[i][j] = 0.f;
#pragma unroll
            for (int d = 0; d < 64; ++d) {
                float4 a4 = *(float4*)&Xs[d][ty * 4];
                float4 w4 = *(float4*)&Ws[pj][d][tx * 4];
                float a[4] = {a4.x, a4.y, a4.z, a4.w};
                float w[4] = {w4.x, w4.y, w4.z, w4.w};
#pragma unroll
                for (int i = 0; i < 4; ++i)
#pragma unroll
                    for (int j = 0; j < 4; ++j) acc[i][j] += a[i] * w[j];
            }
            const float* bp = (pj == 0) ? bq : (pj == 1) ? bk : bv;
            float4 bias = *(const float4*)&bp[h * 64 + tx * 4];
            float* dst = (pj == 0) ? q : (pj == 1) ? k : v;
#pragma unroll
            for (int i = 0; i < 4; ++i) {
                int sg = s0 + ty * 4 + i;
                if (sg < SEQL) {
                    float4 o;
                    o.x = acc[i][0] + bias.x;
                    o.y = acc[i][1] + bias.y;
                    o.z = acc[i][2] + bias.z;
                    o.w = acc[i][3] + bias.w;
                    *(float4*)&dst[base + (long)sg * 64 + tx * 4] = o;
                }
            }
        }
    }
}

// ---------------- flash attention + residual: out = tokens + softmax(QK^T/8)@V ----
__launch_bounds__(256)
__global__ void k_attn(const float* __restrict__ q, const float* __restrict__ k,
                       const float* __restrict__ v, const float* __restrict__ tok,
                       float* __restrict__ out) {
    const int qt = blockIdx.x, h = blockIdx.y, b = blockIdx.z;
    __shared__ float Qs[64][68];   // [d][r]
    __shared__ float KVs[64][68];  // K: [d][t] ; V: [t][e]
    __shared__ float Ps[64][68];   // [t][r]
    const int tid = threadIdx.x, tx = tid & 15, ty = tid >> 4;
    const long base = (long)(b * 12 + h) * SEQL * 64;
    const int r0 = qt * 64;

#pragma unroll
    for (int l = 0; l < 4; ++l) {
        int ii = tid + l * 256;
        int r = ii >> 4, dq = ii & 15;
        float4 qv = {0.f, 0.f, 0.f, 0.f};
        if (r0 + r < SEQL) qv = *(const float4*)&q[base + (long)(r0 + r) * 64 + dq * 4];
        Qs[dq * 4 + 0][r] = qv.x;
        Qs[dq * 4 + 1][r] = qv.y;
        Qs[dq * 4 + 2][r] = qv.z;
        Qs[dq * 4 + 3][r] = qv.w;
    }

    float m_i[4], l_i[4], acc[4][4];
#pragma unroll
    for (int i = 0; i < 4; ++i) {
        m_i[i] = -INFINITY;
        l_i[i] = 0.f;
#pragma unroll
        for (int j = 0; j < 4; ++j) acc[i][j] = 0.f;
    }

    for (int tt = 0; tt < 4; ++tt) {
        const int t0 = tt * 64;
        __syncthreads();   // protects KVs reuse (and covers initial Qs load)
#pragma unroll
        for (int l = 0; l < 4; ++l) {
            int ii = tid + l * 256;
            int t = ii >> 4, dq = ii & 15;
            float4 kv = {0.f, 0.f, 0.f, 0.f};
            if (t0 + t < SEQL) kv = *(const float4*)&k[base + (long)(t0 + t) * 64 + dq * 4];
            KVs[dq * 4 + 0][t] = kv.x;
            KVs[dq * 4 + 1][t] = kv.y;
            KVs[dq * 4 + 2][t] = kv.z;
            KVs[dq * 4 + 3][t] = kv.w;
        }
        __syncthreads();

        float sa[4][4];
#pragma unroll
        for (int i = 0; i < 4; ++i)
#pragma unroll
            for (int j = 0; j < 4; ++j) sa[i][j] = 0.f;
#pragma unroll
        for (int d = 0; d < 64; ++d) {
            float4 a4 = *(float4*)&Qs[d][ty * 4];
            float4 b4 = *(float4*)&KVs[d][tx * 4];
            float a[4] = {a4.x, a4.y, a4.z, a4.w};
            float bb[4] = {b4.x, b4.y, b4.z, b4.w};
#pragma unroll
            for (int i = 0; i < 4; ++i)
#pragma unroll
                for (int j = 0; j < 4; ++j) sa[i][j] += a[i] * bb[j];
        }

        float pr[4][4];
#pragma unroll
        for (int i = 0; i < 4; ++i) {
            float mt = -INFINITY;
#pragma unroll
            for (int j = 0; j < 4; ++j) {
                float sv = sa[i][j] * 0.125f;
                if (t0 + tx * 4 + j >= SEQL) sv = -1e30f;
                sa[i][j] = sv;
                mt = fmaxf(mt, sv);
            }
            mt = fmaxf(mt, __shfl_xor(mt, 1));
            mt = fmaxf(mt, __shfl_xor(mt, 2));
            mt = fmaxf(mt, __shfl_xor(mt, 4));
            mt = fmaxf(mt, __shfl_xor(mt, 8));
            float mn = fmaxf(m_i[i], mt);
            float alpha = __expf(m_i[i] - mn);
            float rsum = 0.f;
#pragma unroll
            for (int j = 0; j < 4; ++j) {
                float p = __expf(sa[i][j] - mn);
                pr[i][j] = p;
                rsum += p;
            }
            rsum += __shfl_xor(rsum, 1);
            rsum += __shfl_xor(rsum, 2);
            rsum += __shfl_xor(rsum, 4);
            rsum += __shfl_xor(rsum, 8);
            l_i[i] = l_i[i] * alpha + rsum;
            m_i[i] = mn;
#pragma unroll
            for (int j = 0; j < 4; ++j) acc[i][j] *= alpha;
#pragma unroll
            for (int j = 0; j < 4; ++j) Ps[tx * 4 + j][ty * 4 + i] = pr[i][j];
        }
        __syncthreads();   // S-micro done reading KVs; Ps written
        // stage V natural [t][e]
#pragma unroll
        for (int l = 0; l < 4; ++l) {
            int ii = tid + l * 256;
            int t = ii >> 4, dq = ii & 15;
            float4 vv = {0.f, 0.f, 0.f, 0.f};
            if (t0 + t < SEQL) vv = *(const float4*)&v[base + (long)(t0 + t) * 64 + dq * 4];
            *(float4*)&KVs[t][dq * 4] = vv;
        }
        __syncthreads();
#pragma unroll
        for (int t = 0; t < 64; ++t) {
            float4 a4 = *(float4*)&Ps[t][ty * 4];
            float4 b4 = *(float4*)&KVs[t][tx * 4];
            float a[4] = {a4.x, a4.y, a4.z, a4.w};
            float bb[4] = {b4.x, b4.y, b4.z, b4.w};
#pragma unroll
            for (int i = 0; i < 4; ++i)
#pragma unroll
                for (int j = 0; j < 4; ++j) acc[i][j] += a[i] * bb[j];
        }
    }
    // epilogue: O/l + residual
#pragma unroll
    for (int i = 0; i < 4; ++i) {
        int r = r0 + ty * 4 + i;
        if (r < SEQL) {
            float inv = 1.0f / l_i[i];
            int off = (b * SEQL + r) * HD + h * 64 + tx * 4;
            float4 t4 = *(const float4*)&tok[off];
            float4 o;
            o.x = acc[i][0] * inv + t4.x;
            o.y = acc[i][1] * inv + t4.y;
            o.z = acc[i][2] * inv + t4.z;
            o.w = acc[i][3] * inv + t4.w;
            *(float4*)&out[off] = o;
        }
    }
}

// ---------------- LN2 apply (elementwise) ----------------
__global__ void k_ln2apply(const float* __restrict__ outb, const float* __restrict__ stats,
                           const float* __restrict__ g2, const float* __restrict__ b2,
                           float* __restrict__ x) {
    int i = blockIdx.x * 256 + threadIdx.x;   // vec4 index
    if (i >= BATCH * SEQL * HD / 4) return;
    int e4 = i * 4;
    int m = e4 / HD, kk = e4 % HD;
    int b = m / SEQL, s = m % SEQL;
    float mu = stats[128 + b * 2], rsg = stats[128 + b * 2 + 1];
    float4 t = *(const float4*)&outb[e4];
    float4 g = *(const float4*)&g2[s * HD + kk];
    float4 bb = *(const float4*)&b2[s * HD + kk];
    float4 o;
    o.x = (t.x - mu) * rsg * g.x + bb.x;
    o.y = (t.y - mu) * rsg * g.y + bb.y;
    o.z = (t.z - mu) * rsg * g.z + bb.z;
    o.w = (t.w - mu) * rsg * g.w + bb.w;
    *(float4*)&x[e4] = o;
}

// ---------------- encoder MLP GEMM: out += relu(x @ W_enc + b_enc) ----------------
// M = 64*197 = 12608 (99 tiles of 128, last partial), N = 768, K = 768
__launch_bounds__(256)
__global__ void k_enc(const float* __restrict__ A, const float* __restrict__ W,
                      const float* __restrict__ be, float* __restrict__ out) {
    __shared__ float As[16][132];
    __shared__ float Bs[16][132];
    const int m0 = blockIdx.x * 128;
    const int n0 = blockIdx.y * 128;
    const int tid = threadIdx.x;
    const int tx = tid & 15, ty = tid >> 4;

    float acc[8][8];
#pragma unroll
    for (int i = 0; i < 8; ++i)
#pragma unroll
        for (int j = 0; j < 8; ++j) acc[i][j] = 0.f;

    for (int k0 = 0; k0 < 768; k0 += 16) {
#pragma unroll
        for (int l = 0; l < 2; ++l) {
            int ii = tid + l * 256;
            int row = ii >> 2, kq = ii & 3;
            int m = m0 + row;
            float4 av = {0.f, 0.f, 0.f, 0.f};
            if (m < BATCH * SEQL) av = *(const float4*)&A[m * 768 + k0 + kq * 4];
            As[kq * 4 + 0][row] = av.x;
            As[kq * 4 + 1][row] = av.y;
            As[kq * 4 + 2][row] = av.z;
            As[kq * 4 + 3][row] = av.w;
        }
#pragma unroll
        for (int l = 0; l < 2; ++l) {
            int ii = tid + l * 256;
            int kr = ii >> 5, nq = ii & 31;
            *(float4*)&Bs[kr][nq * 4] = *(const float4*)&W[(k0 + kr) * 768 + n0 + nq * 4];
        }
        __syncthreads();
#pragma unroll
        for (int kk = 0; kk < 16; ++kk) {
            float a[8], bv[8];
            *(float4*)&a[0] = *(float4*)&As[kk][ty * 8];
            *(float4*)&a[4] = *(float4*)&As[kk][ty * 8 + 4];
            *(float4*)&bv[0] = *(float4*)&Bs[kk][tx * 8];
            *(float4*)&bv[4] = *(float4*)&Bs[kk][tx * 8 + 4];
#pragma unroll
            for (int i = 0; i < 8; ++i)
#pragma unroll
                for (int j = 0; j < 8; ++j) acc[i][j] += a[i] * bv[j];
        }
        __syncthreads();
    }
#pragma unroll
    for (int i = 0; i < 8; ++i) {
        int m = m0 + ty * 8 + i;
        if (m < BATCH * SEQL) {
            float* dst = &out[m * 768 + n0 + tx * 8];
            const float* bb = &be[n0 + tx * 8];
#pragma unroll
            for (int jq = 0; jq < 2; ++jq) {
                float4 cur = *(float4*)&dst[jq * 4];
                float4 o;
                o.x = cur.x + fmaxf(acc[i][jq * 4 + 0] + bb[jq * 4 + 0], 0.f);
                o.y = cur.y + fmaxf(acc[i][jq * 4 + 1] + bb[jq * 4 + 1], 0.f);
                o.z = cur.z + fmaxf(acc[i][jq * 4 + 2] + bb[jq * 4 + 2], 0.f);
                o.w = cur.w + fmaxf(acc[i][jq * 4 + 3] + bb[jq * 4 + 3], 0.f);
                *(float4*)&dst[jq * 4] = o;
            }
        }
    }
}

// ---------------- classifier head + softmax ----------------
__launch_bounds__(256)
__global__ void k_head(const float* __restrict__ out, const float* __restrict__ Wo,
                       const float* __restrict__ bo, float* __restrict__ dout) {
    const int b = blockIdx.x, tid = threadIdx.x;
    __shared__ float cls[768];
    __shared__ float red[256];
    for (int i = tid; i < 192; i += 256)
        *(float4*)&cls[i * 4] = *(const float4*)&out[(b * SEQL) * HD + i * 4];
    __syncthreads();

    const int o0 = tid * 4;
    const bool ok = (o0 < OUTD);
    float4 acc = {0.f, 0.f, 0.f, 0.f};
    if (ok) {
        acc = *(const float4*)&bo[o0];
        for (int e = 0; e < 768; ++e) {
            float c = cls[e];
            float4 w = *(const float4*)&Wo[e * OUTD + o0];
            acc.x += c * w.x;
            acc.y += c * w.y;
            acc.z += c * w.z;
            acc.w += c * w.w;
        }
    }
    float mx = ok ? fmaxf(fmaxf(acc.x, acc.y), fmaxf(acc.z, acc.w)) : -INFINITY;
    red[tid] = mx;
    __syncthreads();
    for (int s = 128; s > 0; s >>= 1) {
        if (tid < s) red[tid] = fmaxf(red[tid], red[tid + s]);
        __syncthreads();
    }
    float M = red[0];
    __syncthreads();
    float4 p = {0.f, 0.f, 0.f, 0.f};
    float ls = 0.f;
    if (ok) {
        p.x = expf(acc.x - M);
        p.y = expf(acc.y - M);
        p.z = expf(acc.z - M);
        p.w = expf(acc.w - M);
        ls = p.x + p.y + p.z + p.w;
    }
    red[tid] = ls;
    __syncthreads();
    for (int s = 128; s > 0; s >>= 1) {
        if (tid < s) red[tid] += red[tid + s];
        __syncthreads();
    }
    float inv = 1.0f / red[0];
    if (ok) {
        p.x *= inv; p.y *= inv; p.z *= inv; p.w *= inv;
        *(float4*)&dout[b * OUTD + o0] = p;
    }
}

extern "C" void kernel_launch(void* const* d_in, const int* in_sizes, int n_in,
                              void* d_out, int out_size, void* d_ws, size_t ws_size,
                              hipStream_t stream) {
    const float* images  = (const float*)d_in[0];
    const float* W_map   = (const float*)d_in[1];
    const float* b_map   = (const float*)d_in[2];
    const float* cls_tok = (const float*)d_in[3];
    const float* ln1_g   = (const float*)d_in[4];
    const float* ln1_b   = (const float*)d_in[5];
    const float* Wq      = (const float*)d_in[6];
    const float* bq      = (const float*)d_in[7];
    const float* Wk      = (const float*)d_in[8];
    const float* bk      = (const float*)d_in[9];
    const float* Wv      = (const float*)d_in[10];
    const float* bv      = (const float*)d_in[11];
    const float* ln2_g   = (const float*)d_in[12];
    const float* ln2_b   = (const float*)d_in[13];
    const float* W_enc   = (const float*)d_in[14];
    const float* b_enc   = (const float*)d_in[15];
    const float* W_out   = (const float*)d_in[16];
    const float* b_out   = (const float*)d_in[17];

    float* ws = (float*)d_ws;
    const size_t BIG = (size_t)BATCH * SEQL * HD;   // 9,682,944
    float* pos   = ws;
    float* tok   = ws + 151552;
    float* outb  = tok + BIG;
    float* qb    = outb + BIG;
    float* kb    = qb + BIG;
    float* vb    = kb + BIG;
    float* stats = vb + BIG;                        // 256 floats

    k_pos<<<591, 256, 0, stream>>>(pos);
    k_cls<<<192, 256, 0, stream>>>(cls_tok, pos, tok);
    k_embed<<<dim3(98, 6), 256, 0, stream>>>(images, W_map, b_map, pos, tok);
    k_lnstats<<<64, 256, 0, stream>>>(tok, stats, 0);
    k_qkv<<<768, 256, 0, stream>>>(tok, stats, ln1_g, ln1_b, Wq, bq, Wk, bk, Wv, bv, qb, kb, vb);
    k_attn<<<dim3(4, 12, 64), 256, 0, stream>>>(qb, kb, vb, tok, outb);
    k_lnstats<<<64, 256, 0, stream>>>(outb, stats, 1);
    k_ln2apply<<<9456, 256, 0, stream>>>(outb, stats, ln2_g, ln2_b, qb);
    k_enc<<<dim3(99, 6), 256, 0, stream>>>(qb, W_enc, b_enc, outb);
    k_head<<<64, 256, 0, stream>>>(outb, W_out, b_out, (float*)d_out);
}

// Round 2
// 958.317 us; speedup vs baseline: 1.6863x; 1.6863x over previous
//
#include <hip/hip_runtime.h>
#include <math.h>

#define SEQL 197
#define HD 768
#define NH 12
#define DHD 64
#define BATCH 64
#define OUTD 1000

// ---------------- positional embedding table ----------------
__global__ void k_pos(float* __restrict__ pos) {
    int i = blockIdx.x * 256 + threadIdx.x;
    if (i >= SEQL * HD) return;
    int s = i / HD, d = i % HD;
    float f = (float)(d & ~1);
    float r = powf(10000.0f, -f / (float)HD);
    float a = (float)s * r;
    pos[i] = (d & 1) ? cosf(a) : sinf(a);
}

// ---------------- cls row of tokens ----------------
__global__ void k_cls(const float* __restrict__ cls_tok, const float* __restrict__ pos,
                      float* __restrict__ tok) {
    int i = blockIdx.x * 256 + threadIdx.x;
    if (i >= BATCH * HD) return;
    int b = i / HD, e = i % HD;
    tok[(b * SEQL) * HD + e] = cls_tok[e] + pos[e];
}

// ---------------- patch embed GEMM: tokens[s>=1] = patches @ W_map + b_map + pos ----
// M = 64*196 = 12544 (exact 98*128), N = 768 (6*128), K = 768
__launch_bounds__(256)
__global__ void k_embed(const float* __restrict__ img, const float* __restrict__ Wm,
                        const float* __restrict__ bm, const float* __restrict__ pos,
                        float* __restrict__ tok) {
    __shared__ float As[16][132];
    __shared__ float Bs[16][132];
    const int m0 = blockIdx.x * 128;
    const int n0 = blockIdx.y * 128;
    const int tid = threadIdx.x;
    const int tx = tid & 15, ty = tid >> 4;

    float acc[8][8];
#pragma unroll
    for (int i = 0; i < 8; ++i)
#pragma unroll
        for (int j = 0; j < 8; ++j) acc[i][j] = 0.f;

    for (int k0 = 0; k0 < 768; k0 += 16) {
        // stage A: gather from images. k = c*256 + ir*16 + j ; 16 k's contiguous.
        const int c = k0 >> 8;
        const int ir = (k0 & 255) >> 4;
#pragma unroll
        for (int l = 0; l < 2; ++l) {
            int ii = tid + l * 256;            // 0..511
            int row = ii >> 2, kq = ii & 3;
            int m = m0 + row;
            int b = m / 196, pi = m % 196;
            int pr = pi / 14, pc = pi % 14;
            const float4 av = *(const float4*)&img[((b * 3 + c) * 224 + pr * 16 + ir) * 224 + pc * 16 + kq * 4];
            As[kq * 4 + 0][row] = av.x;
            As[kq * 4 + 1][row] = av.y;
            As[kq * 4 + 2][row] = av.z;
            As[kq * 4 + 3][row] = av.w;
        }
        // stage B
#pragma unroll
        for (int l = 0; l < 2; ++l) {
            int ii = tid + l * 256;            // 0..511
            int kr = ii >> 5, nq = ii & 31;
            *(float4*)&Bs[kr][nq * 4] = *(const float4*)&Wm[(k0 + kr) * 768 + n0 + nq * 4];
        }
        __syncthreads();
#pragma unroll
        for (int kk = 0; kk < 16; ++kk) {
            float a[8], bv[8];
            *(float4*)&a[0] = *(float4*)&As[kk][ty * 8];
            *(float4*)&a[4] = *(float4*)&As[kk][ty * 8 + 4];
            *(float4*)&bv[0] = *(float4*)&Bs[kk][tx * 8];
            *(float4*)&bv[4] = *(float4*)&Bs[kk][tx * 8 + 4];
#pragma unroll
            for (int i = 0; i < 8; ++i)
#pragma unroll
                for (int j = 0; j < 8; ++j) acc[i][j] += a[i] * bv[j];
        }
        __syncthreads();
    }
    // epilogue: + b_map + pos, write tokens rows s>=1
#pragma unroll
    for (int i = 0; i < 8; ++i) {
        int m = m0 + ty * 8 + i;
        int b = m / 196, s = 1 + m % 196;
        float* dst = &tok[((b * SEQL) + s) * HD + n0 + tx * 8];
        const float* pp = &pos[s * HD + n0 + tx * 8];
        const float* bb = &bm[n0 + tx * 8];
#pragma unroll
        for (int jq = 0; jq < 2; ++jq) {
            float4 o;
            o.x = acc[i][jq * 4 + 0] + pp[jq * 4 + 0] + bb[jq * 4 + 0];
            o.y = acc[i][jq * 4 + 1] + pp[jq * 4 + 1] + bb[jq * 4 + 1];
            o.z = acc[i][jq * 4 + 2] + pp[jq * 4 + 2] + bb[jq * 4 + 2];
            o.w = acc[i][jq * 4 + 3] + pp[jq * 4 + 3] + bb[jq * 4 + 3];
            *(float4*)&dst[jq * 4] = o;
        }
    }
}

// ---------------- 2D LayerNorm stats (mean, rsigma) per image ----------------
__global__ void k_lnstats(const float* __restrict__ buf, float* __restrict__ stats, int which) {
    int b = blockIdx.x;
    const float* p = buf + (size_t)b * SEQL * HD;
    float s = 0.f, s2 = 0.f;
    const int NV = SEQL * HD / 4;   // 37824
    for (int i = threadIdx.x; i < NV; i += 256) {
        float4 v = ((const float4*)p)[i];
        s += v.x + v.y + v.z + v.w;
        s2 += v.x * v.x + v.y * v.y + v.z * v.z + v.w * v.w;
    }
    __shared__ float rs[8], rs2[8];
#pragma unroll
    for (int off = 32; off > 0; off >>= 1) {
        s += __shfl_down(s, off);
        s2 += __shfl_down(s2, off);
    }
    int lane = threadIdx.x & 63, w = threadIdx.x >> 6;
    if (lane == 0) { rs[w] = s; rs2[w] = s2; }
    __syncthreads();
    if (threadIdx.x == 0) {
        float S = 0.f, S2 = 0.f;
        for (int i = 0; i < 4; ++i) { S += rs[i]; S2 += rs2[i]; }
        const float inv_n = 1.0f / (float)(SEQL * HD);
        float mu = S * inv_n;
        float var = S2 * inv_n - mu * mu;
        stats[which * 128 + b * 2] = mu;
        stats[which * 128 + b * 2 + 1] = rsqrtf(var + 1e-5f);
    }
}

// ---------------- QKV projections (LN1 fused on load) ----------------
// block per (h, pj, b); 8x8 microtile; q/k/v layout: [(b*12+h)][s][e]
__launch_bounds__(256)
__global__ void k_qkv(const float* __restrict__ tok, const float* __restrict__ stats,
                      const float* __restrict__ g1, const float* __restrict__ b1,
                      const float* __restrict__ Wq, const float* __restrict__ bq,
                      const float* __restrict__ Wk, const float* __restrict__ bk,
                      const float* __restrict__ Wv, const float* __restrict__ bv,
                      float* __restrict__ q, float* __restrict__ k, float* __restrict__ v) {
    const int h = blockIdx.x, pj = blockIdx.y, b = blockIdx.z;
    __shared__ float Ws[64][68];    // [d][e]
    __shared__ float Xs[32][260];   // [d-chunk][s]  (s padded to 256, 260 stride)
    const int tid = threadIdx.x;
    const int sg = tid >> 3, eg = tid & 7;   // 32 s-groups x 8 e-groups

    const float* W  = (pj == 0) ? Wq : (pj == 1) ? Wk : Wv;
    const float* bp = (pj == 0) ? bq : (pj == 1) ? bk : bv;
    float* dst      = (pj == 0) ? q  : (pj == 1) ? k  : v;

    // stage W: 64x64
#pragma unroll
    for (int l = 0; l < 4; ++l) {
        int ii = tid + l * 256;            // 0..1023
        int d = ii >> 4, eq = ii & 15;
        *(float4*)&Ws[d][eq * 4] = *(const float4*)&W[(h * 64 + d) * 64 + eq * 4];
    }
    const float mu = stats[b * 2], rsg = stats[b * 2 + 1];
    const long base = (long)(b * 12 + h) * SEQL * 64;

    float acc[8][8];
#pragma unroll
    for (int i = 0; i < 8; ++i)
#pragma unroll
        for (int j = 0; j < 8; ++j) acc[i][j] = 0.f;

    for (int kc = 0; kc < 2; ++kc) {
        __syncthreads();
        // stage X chunk: d in [kc*32, kc*32+32), s in [0,256), LN1 applied
#pragma unroll
        for (int l = 0; l < 8; ++l) {
            int ii = tid + l * 256;        // 0..2047
            int s = ii >> 3, dq = ii & 7;
            float4 xv = {0.f, 0.f, 0.f, 0.f};
            if (s < SEQL) {
                int off = (b * SEQL + s) * HD + h * 64 + kc * 32 + dq * 4;
                int loff = s * HD + h * 64 + kc * 32 + dq * 4;
                float4 t4 = *(const float4*)&tok[off];
                float4 g4 = *(const float4*)&g1[loff];
                float4 bb4 = *(const float4*)&b1[loff];
                xv.x = (t4.x - mu) * rsg * g4.x + bb4.x;
                xv.y = (t4.y - mu) * rsg * g4.y + bb4.y;
                xv.z = (t4.z - mu) * rsg * g4.z + bb4.z;
                xv.w = (t4.w - mu) * rsg * g4.w + bb4.w;
            }
            Xs[dq * 4 + 0][s] = xv.x;
            Xs[dq * 4 + 1][s] = xv.y;
            Xs[dq * 4 + 2][s] = xv.z;
            Xs[dq * 4 + 3][s] = xv.w;
        }
        __syncthreads();
#pragma unroll
        for (int d = 0; d < 32; ++d) {
            float a[8], w[8];
            *(float4*)&a[0] = *(float4*)&Xs[d][sg * 8];
            *(float4*)&a[4] = *(float4*)&Xs[d][sg * 8 + 4];
            *(float4*)&w[0] = *(float4*)&Ws[kc * 32 + d][eg * 8];
            *(float4*)&w[4] = *(float4*)&Ws[kc * 32 + d][eg * 8 + 4];
#pragma unroll
            for (int i = 0; i < 8; ++i)
#pragma unroll
                for (int j = 0; j < 8; ++j) acc[i][j] += a[i] * w[j];
        }
    }
    // epilogue: + bias, write
    float4 bias0 = *(const float4*)&bp[h * 64 + eg * 8];
    float4 bias1 = *(const float4*)&bp[h * 64 + eg * 8 + 4];
#pragma unroll
    for (int i = 0; i < 8; ++i) {
        int s = sg * 8 + i;
        if (s < SEQL) {
            float4 o0, o1;
            o0.x = acc[i][0] + bias0.x;
            o0.y = acc[i][1] + bias0.y;
            o0.z = acc[i][2] + bias0.z;
            o0.w = acc[i][3] + bias0.w;
            o1.x = acc[i][4] + bias1.x;
            o1.y = acc[i][5] + bias1.y;
            o1.z = acc[i][6] + bias1.z;
            o1.w = acc[i][7] + bias1.w;
            *(float4*)&dst[base + (long)s * 64 + eg * 8] = o0;
            *(float4*)&dst[base + (long)s * 64 + eg * 8 + 4] = o1;
        }
    }
}

// ---------------- flash attention + residual: out = tokens + softmax(QK^T/8)@V ----
__launch_bounds__(256)
__global__ void k_attn(const float* __restrict__ q, const float* __restrict__ k,
                       const float* __restrict__ v, const float* __restrict__ tok,
                       float* __restrict__ out) {
    const int qt = blockIdx.x, h = blockIdx.y, b = blockIdx.z;
    __shared__ float Qs[64][68];   // [d][r]
    __shared__ float KVs[64][68];  // K: [d][t] ; V: [t][e]
    __shared__ float Ps[64][68];   // [t][r]
    const int tid = threadIdx.x, tx = tid & 15, ty = tid >> 4;
    const long base = (long)(b * 12 + h) * SEQL * 64;
    const int r0 = qt * 64;

#pragma unroll
    for (int l = 0; l < 4; ++l) {
        int ii = tid + l * 256;
        int r = ii >> 4, dq = ii & 15;
        float4 qv = {0.f, 0.f, 0.f, 0.f};
        if (r0 + r < SEQL) qv = *(const float4*)&q[base + (long)(r0 + r) * 64 + dq * 4];
        Qs[dq * 4 + 0][r] = qv.x;
        Qs[dq * 4 + 1][r] = qv.y;
        Qs[dq * 4 + 2][r] = qv.z;
        Qs[dq * 4 + 3][r] = qv.w;
    }

    float m_i[4], l_i[4], acc[4][4];
#pragma unroll
    for (int i = 0; i < 4; ++i) {
        m_i[i] = -INFINITY;
        l_i[i] = 0.f;
#pragma unroll
        for (int j = 0; j < 4; ++j) acc[i][j] = 0.f;
    }

    for (int tt = 0; tt < 4; ++tt) {
        const int t0 = tt * 64;
        __syncthreads();   // protects KVs reuse (and covers initial Qs load)
#pragma unroll
        for (int l = 0; l < 4; ++l) {
            int ii = tid + l * 256;
            int t = ii >> 4, dq = ii & 15;
            float4 kv = {0.f, 0.f, 0.f, 0.f};
            if (t0 + t < SEQL) kv = *(const float4*)&k[base + (long)(t0 + t) * 64 + dq * 4];
            KVs[dq * 4 + 0][t] = kv.x;
            KVs[dq * 4 + 1][t] = kv.y;
            KVs[dq * 4 + 2][t] = kv.z;
            KVs[dq * 4 + 3][t] = kv.w;
        }
        __syncthreads();

        float sa[4][4];
#pragma unroll
        for (int i = 0; i < 4; ++i)
#pragma unroll
            for (int j = 0; j < 4; ++j) sa[i][j] = 0.f;
#pragma unroll
        for (int d = 0; d < 64; ++d) {
            float4 a4 = *(float4*)&Qs[d][ty * 4];
            float4 b4 = *(float4*)&KVs[d][tx * 4];
            float a[4] = {a4.x, a4.y, a4.z, a4.w};
            float bb[4] = {b4.x, b4.y, b4.z, b4.w};
#pragma unroll
            for (int i = 0; i < 4; ++i)
#pragma unroll
                for (int j = 0; j < 4; ++j) sa[i][j] += a[i] * bb[j];
        }

        float pr[4][4];
#pragma unroll
        for (int i = 0; i < 4; ++i) {
            float mt = -INFINITY;
#pragma unroll
            for (int j = 0; j < 4; ++j) {
                float sv = sa[i][j] * 0.125f;
                if (t0 + tx * 4 + j >= SEQL) sv = -1e30f;
                sa[i][j] = sv;
                mt = fmaxf(mt, sv);
            }
            mt = fmaxf(mt, __shfl_xor(mt, 1));
            mt = fmaxf(mt, __shfl_xor(mt, 2));
            mt = fmaxf(mt, __shfl_xor(mt, 4));
            mt = fmaxf(mt, __shfl_xor(mt, 8));
            float mn = fmaxf(m_i[i], mt);
            float alpha = __expf(m_i[i] - mn);
            float rsum = 0.f;
#pragma unroll
            for (int j = 0; j < 4; ++j) {
                float p = __expf(sa[i][j] - mn);
                pr[i][j] = p;
                rsum += p;
            }
            rsum += __shfl_xor(rsum, 1);
            rsum += __shfl_xor(rsum, 2);
            rsum += __shfl_xor(rsum, 4);
            rsum += __shfl_xor(rsum, 8);
            l_i[i] = l_i[i] * alpha + rsum;
            m_i[i] = mn;
#pragma unroll
            for (int j = 0; j < 4; ++j) acc[i][j] *= alpha;
#pragma unroll
            for (int j = 0; j < 4; ++j) Ps[tx * 4 + j][ty * 4 + i] = pr[i][j];
        }
        __syncthreads();   // S-micro done reading KVs; Ps written
        // stage V natural [t][e]
#pragma unroll
        for (int l = 0; l < 4; ++l) {
            int ii = tid + l * 256;
            int t = ii >> 4, dq = ii & 15;
            float4 vv = {0.f, 0.f, 0.f, 0.f};
            if (t0 + t < SEQL) vv = *(const float4*)&v[base + (long)(t0 + t) * 64 + dq * 4];
            *(float4*)&KVs[t][dq * 4] = vv;
        }
        __syncthreads();
#pragma unroll
        for (int t = 0; t < 64; ++t) {
            float4 a4 = *(float4*)&Ps[t][ty * 4];
            float4 b4 = *(float4*)&KVs[t][tx * 4];
            float a[4] = {a4.x, a4.y, a4.z, a4.w};
            float bb[4] = {b4.x, b4.y, b4.z, b4.w};
#pragma unroll
            for (int i = 0; i < 4; ++i)
#pragma unroll
                for (int j = 0; j < 4; ++j) acc[i][j] += a[i] * bb[j];
        }
    }
    // epilogue: O/l + residual
#pragma unroll
    for (int i = 0; i < 4; ++i) {
        int r = r0 + ty * 4 + i;
        if (r < SEQL) {
            float inv = 1.0f / l_i[i];
            int off = (b * SEQL + r) * HD + h * 64 + tx * 4;
            float4 t4 = *(const float4*)&tok[off];
            float4 o;
            o.x = acc[i][0] * inv + t4.x;
            o.y = acc[i][1] * inv + t4.y;
            o.z = acc[i][2] * inv + t4.z;
            o.w = acc[i][3] * inv + t4.w;
            *(float4*)&out[off] = o;
        }
    }
}

// ---------------- LN2 apply (elementwise) ----------------
__global__ void k_ln2apply(const float* __restrict__ outb, const float* __restrict__ stats,
                           const float* __restrict__ g2, const float* __restrict__ b2,
                           float* __restrict__ x) {
    int i = blockIdx.x * 256 + threadIdx.x;   // vec4 index
    if (i >= BATCH * SEQL * HD / 4) return;
    int e4 = i * 4;
    int m = e4 / HD, kk = e4 % HD;
    int b = m / SEQL, s = m % SEQL;
    float mu = stats[128 + b * 2], rsg = stats[128 + b * 2 + 1];
    float4 t = *(const float4*)&outb[e4];
    float4 g = *(const float4*)&g2[s * HD + kk];
    float4 bb = *(const float4*)&b2[s * HD + kk];
    float4 o;
    o.x = (t.x - mu) * rsg * g.x + bb.x;
    o.y = (t.y - mu) * rsg * g.y + bb.y;
    o.z = (t.z - mu) * rsg * g.z + bb.z;
    o.w = (t.w - mu) * rsg * g.w + bb.w;
    *(float4*)&x[e4] = o;
}

// ---------------- encoder MLP GEMM: out += relu(x @ W_enc + b_enc) ----------------
// M = 64*197 = 12608 (99 tiles of 128, last partial), N = 768, K = 768
__launch_bounds__(256)
__global__ void k_enc(const float* __restrict__ A, const float* __restrict__ W,
                      const float* __restrict__ be, float* __restrict__ out) {
    __shared__ float As[16][132];
    __shared__ float Bs[16][132];
    const int m0 = blockIdx.x * 128;
    const int n0 = blockIdx.y * 128;
    const int tid = threadIdx.x;
    const int tx = tid & 15, ty = tid >> 4;

    float acc[8][8];
#pragma unroll
    for (int i = 0; i < 8; ++i)
#pragma unroll
        for (int j = 0; j < 8; ++j) acc[i][j] = 0.f;

    for (int k0 = 0; k0 < 768; k0 += 16) {
#pragma unroll
        for (int l = 0; l < 2; ++l) {
            int ii = tid + l * 256;
            int row = ii >> 2, kq = ii & 3;
            int m = m0 + row;
            float4 av = {0.f, 0.f, 0.f, 0.f};
            if (m < BATCH * SEQL) av = *(const float4*)&A[m * 768 + k0 + kq * 4];
            As[kq * 4 + 0][row] = av.x;
            As[kq * 4 + 1][row] = av.y;
            As[kq * 4 + 2][row] = av.z;
            As[kq * 4 + 3][row] = av.w;
        }
#pragma unroll
        for (int l = 0; l < 2; ++l) {
            int ii = tid + l * 256;
            int kr = ii >> 5, nq = ii & 31;
            *(float4*)&Bs[kr][nq * 4] = *(const float4*)&W[(k0 + kr) * 768 + n0 + nq * 4];
        }
        __syncthreads();
#pragma unroll
        for (int kk = 0; kk < 16; ++kk) {
            float a[8], bv[8];
            *(float4*)&a[0] = *(float4*)&As[kk][ty * 8];
            *(float4*)&a[4] = *(float4*)&As[kk][ty * 8 + 4];
            *(float4*)&bv[0] = *(float4*)&Bs[kk][tx * 8];
            *(float4*)&bv[4] = *(float4*)&Bs[kk][tx * 8 + 4];
#pragma unroll
            for (int i = 0; i < 8; ++i)
#pragma unroll
                for (int j = 0; j < 8; ++j) acc[i][j] += a[i] * bv[j];
        }
        __syncthreads();
    }
#pragma unroll
    for (int i = 0; i < 8; ++i) {
        int m = m0 + ty * 8 + i;
        if (m < BATCH * SEQL) {
            float* dst = &out[m * 768 + n0 + tx * 8];
            const float* bb = &be[n0 + tx * 8];
#pragma unroll
            for (int jq = 0; jq < 2; ++jq) {
                float4 cur = *(float4*)&dst[jq * 4];
                float4 o;
                o.x = cur.x + fmaxf(acc[i][jq * 4 + 0] + bb[jq * 4 + 0], 0.f);
                o.y = cur.y + fmaxf(acc[i][jq * 4 + 1] + bb[jq * 4 + 1], 0.f);
                o.z = cur.z + fmaxf(acc[i][jq * 4 + 2] + bb[jq * 4 + 2], 0.f);
                o.w = cur.w + fmaxf(acc[i][jq * 4 + 3] + bb[jq * 4 + 3], 0.f);
                *(float4*)&dst[jq * 4] = o;
            }
        }
    }
}

// ---------------- classifier head + softmax ----------------
__launch_bounds__(256)
__global__ void k_head(const float* __restrict__ out, const float* __restrict__ Wo,
                       const float* __restrict__ bo, float* __restrict__ dout) {
    const int b = blockIdx.x, tid = threadIdx.x;
    __shared__ float cls[768];
    __shared__ float red[256];
    for (int i = tid; i < 192; i += 256)
        *(float4*)&cls[i * 4] = *(const float4*)&out[(b * SEQL) * HD + i * 4];
    __syncthreads();

    const int o0 = tid * 4;
    const bool ok = (o0 < OUTD);
    float4 acc = {0.f, 0.f, 0.f, 0.f};
    if (ok) {
        acc = *(const float4*)&bo[o0];
        for (int e = 0; e < 768; ++e) {
            float c = cls[e];
            float4 w = *(const float4*)&Wo[e * OUTD + o0];
            acc.x += c * w.x;
            acc.y += c * w.y;
            acc.z += c * w.z;
            acc.w += c * w.w;
        }
    }
    float mx = ok ? fmaxf(fmaxf(acc.x, acc.y), fmaxf(acc.z, acc.w)) : -INFINITY;
    red[tid] = mx;
    __syncthreads();
    for (int s = 128; s > 0; s >>= 1) {
        if (tid < s) red[tid] = fmaxf(red[tid], red[tid + s]);
        __syncthreads();
    }
    float M = red[0];
    __syncthreads();
    float4 p = {0.f, 0.f, 0.f, 0.f};
    float ls = 0.f;
    if (ok) {
        p.x = expf(acc.x - M);
        p.y = expf(acc.y - M);
        p.z = expf(acc.z - M);
        p.w = expf(acc.w - M);
        ls = p.x + p.y + p.z + p.w;
    }
    red[tid] = ls;
    __syncthreads();
    for (int s = 128; s > 0; s >>= 1) {
        if (tid < s) red[tid] += red[tid + s];
        __syncthreads();
    }
    float inv = 1.0f / red[0];
    if (ok) {
        p.x *= inv; p.y *= inv; p.z *= inv; p.w *= inv;
        *(float4*)&dout[b * OUTD + o0] = p;
    }
}

extern "C" void kernel_launch(void* const* d_in, const int* in_sizes, int n_in,
                              void* d_out, int out_size, void* d_ws, size_t ws_size,
                              hipStream_t stream) {
    const float* images  = (const float*)d_in[0];
    const float* W_map   = (const float*)d_in[1];
    const float* b_map   = (const float*)d_in[2];
    const float* cls_tok = (const float*)d_in[3];
    const float* ln1_g   = (const float*)d_in[4];
    const float* ln1_b   = (const float*)d_in[5];
    const float* Wq      = (const float*)d_in[6];
    const float* bq      = (const float*)d_in[7];
    const float* Wk      = (const float*)d_in[8];
    const float* bk      = (const float*)d_in[9];
    const float* Wv      = (const float*)d_in[10];
    const float* bv      = (const float*)d_in[11];
    const float* ln2_g   = (const float*)d_in[12];
    const float* ln2_b   = (const float*)d_in[13];
    const float* W_enc   = (const float*)d_in[14];
    const float* b_enc   = (const float*)d_in[15];
    const float* W_out   = (const float*)d_in[16];
    const float* b_out   = (const float*)d_in[17];

    float* ws = (float*)d_ws;
    const size_t BIG = (size_t)BATCH * SEQL * HD;   // 9,682,944
    float* pos   = ws;
    float* tok   = ws + 151552;
    float* outb  = tok + BIG;
    float* qb    = outb + BIG;
    float* kb    = qb + BIG;
    float* vb    = kb + BIG;
    float* stats = vb + BIG;                        // 256 floats

    k_pos<<<591, 256, 0, stream>>>(pos);
    k_cls<<<192, 256, 0, stream>>>(cls_tok, pos, tok);
    k_embed<<<dim3(98, 6), 256, 0, stream>>>(images, W_map, b_map, pos, tok);
    k_lnstats<<<64, 256, 0, stream>>>(tok, stats, 0);
    k_qkv<<<dim3(12, 3, 64), 256, 0, stream>>>(tok, stats, ln1_g, ln1_b, Wq, bq, Wk, bk, Wv, bv, qb, kb, vb);
    k_attn<<<dim3(4, 12, 64), 256, 0, stream>>>(qb, kb, vb, tok, outb);
    k_lnstats<<<64, 256, 0, stream>>>(outb, stats, 1);
    k_ln2apply<<<9456, 256, 0, stream>>>(outb, stats, ln2_g, ln2_b, qb);
    k_enc<<<dim3(99, 6), 256, 0, stream>>>(qb, W_enc, b_enc, outb);
    k_head<<<64, 256, 0, stream>>>(outb, W_out, b_out, (float*)d_out);
}

// Round 3
// 644.802 us; speedup vs baseline: 2.5062x; 1.4862x over previous
//
#include <hip/hip_runtime.h>
#include <math.h>

#define SEQL 197
#define HD 768
#define NH 12
#define DHD 64
#define BATCH 64
#define OUTD 1000

typedef unsigned short ushort_t;
typedef __attribute__((ext_vector_type(8))) short bf16x8;
typedef __attribute__((ext_vector_type(4))) float f32x4;

static __device__ __forceinline__ unsigned short f2bf(float f) {
    union { float f; unsigned u; } v; v.f = f;
    unsigned r = v.u + 0x7fff + ((v.u >> 16) & 1);
    return (unsigned short)(r >> 16);
}

static __device__ __forceinline__ void gload16(const ushort_t* g, ushort_t* l) {
    __builtin_amdgcn_global_load_lds(
        (const __attribute__((address_space(1))) unsigned int*)g,
        (__attribute__((address_space(3))) unsigned int*)l, 16, 0, 0);
}

// ---------------- positional embedding table ----------------
__global__ void k_pos(float* __restrict__ pos) {
    int i = blockIdx.x * 256 + threadIdx.x;
    if (i >= SEQL * HD) return;
    int s = i / HD, d = i % HD;
    float f = (float)(d & ~1);
    float r = powf(10000.0f, -f / (float)HD);
    float a = (float)s * r;
    pos[i] = (d & 1) ? cosf(a) : sinf(a);
}

// ---------------- cls row of tokens ----------------
__global__ void k_cls(const float* __restrict__ cls_tok, const float* __restrict__ pos,
                      float* __restrict__ tok) {
    int i = blockIdx.x * 256 + threadIdx.x;
    if (i >= BATCH * HD) return;
    int b = i / HD, e = i % HD;
    tok[(b * SEQL) * HD + e] = cls_tok[e] + pos[e];
}

// ---------------- W (f32 [K][N]) -> W^T bf16 [N][K], K=N=768 ----------------
__global__ void k_cvtW(const float* __restrict__ W, ushort_t* __restrict__ WT) {
    int idx = blockIdx.x * 256 + threadIdx.x;       // 0 .. 768*192
    if (idx >= 768 * 192) return;
    int k = idx / 192, nq = idx % 192;
    float4 w = *(const float4*)&W[k * 768 + nq * 4];
    WT[(nq * 4 + 0) * 768 + k] = f2bf(w.x);
    WT[(nq * 4 + 1) * 768 + k] = f2bf(w.y);
    WT[(nq * 4 + 2) * 768 + k] = f2bf(w.z);
    WT[(nq * 4 + 3) * 768 + k] = f2bf(w.w);
}

// ---------------- gather patches -> bf16 A [12544][768] ----------------
__global__ void k_prep_patches(const float* __restrict__ img, ushort_t* __restrict__ Ae) {
    int idx = blockIdx.x * 256 + threadIdx.x;       // 0 .. 12544*192
    int m = idx / 192, kq = idx % 192;
    int k0 = kq * 4;
    int c = k0 >> 8, rem = k0 & 255, ir = rem >> 4, jc = rem & 15;
    int b = m / 196, pi = m % 196;
    int pr = pi / 14, pc = pi % 14;
    float4 v = *(const float4*)&img[((b * 3 + c) * 224 + pr * 16 + ir) * 224 + pc * 16 + jc];
    ushort4 o;
    o.x = f2bf(v.x); o.y = f2bf(v.y); o.z = f2bf(v.z); o.w = f2bf(v.w);
    *(ushort4*)&Ae[m * 768 + k0] = o;
}

// ---------------- bf16 MFMA GEMM, 128x128 tile, BK=64, 4 waves ----------------
// A: bf16 [M][768] row-major. Bt: bf16 [768 n][768 k] (N-major).
// MODE 0 (embed): out=tok; C = A@B + bias[n] + pos[s][n], rows s>=1
// MODE 1 (enc):   out += relu(A@B + bias[n]), mask m < Mtot
template <int MODE>
__launch_bounds__(256)
__global__ void k_gemm_bf16(const ushort_t* __restrict__ A, const ushort_t* __restrict__ Bt,
                            const float* __restrict__ bias, const float* __restrict__ pos,
                            float* __restrict__ out, int Mtot) {
    __shared__ ushort_t As[128 * 64];
    __shared__ ushort_t Bs[128 * 64];
    const int m0 = blockIdx.x * 128;
    const int n0 = blockIdx.y * 128;
    const int tid = threadIdx.x;
    const int lane = tid & 63, wave = tid >> 6;
    const int wm = wave >> 1, wn = wave & 1;

    f32x4 acc[4][4];
#pragma unroll
    for (int i = 0; i < 4; ++i)
#pragma unroll
        for (int j = 0; j < 4; ++j)
#pragma unroll
            for (int r = 0; r < 4; ++r) acc[i][j][r] = 0.f;

    for (int kt = 0; kt < 12; ++kt) {
        const int k0 = kt * 64;
        // stage: 16 chunks of 1KB each for A and B; chunk c covers rows [c*8, c*8+8)
#pragma unroll
        for (int t = 0; t < 4; ++t) {
            int c = (wave << 2) | t;
            int o = c * 1024 + lane * 16;          // phys byte in tile
            int row = o >> 7;
            int inner = o & 127;
            int col = (inner ^ ((row & 7) << 4)) >> 1;   // logical bf16 col 0..63
            gload16(&A[(size_t)(m0 + row) * 768 + k0 + col], &As[c * 512]);
            gload16(&Bt[(size_t)(n0 + row) * 768 + k0 + col], &Bs[c * 512]);
        }
        __syncthreads();
#pragma unroll
        for (int ks = 0; ks < 2; ++ks) {
            const int cbyte = ks * 64 + (lane >> 4) * 16;
            bf16x8 af[4], bf[4];
#pragma unroll
            for (int mi = 0; mi < 4; ++mi) {
                int row = wm * 64 + mi * 16 + (lane & 15);
                af[mi] = *(const bf16x8*)((const char*)As + row * 128 + (cbyte ^ ((row & 7) << 4)));
            }
#pragma unroll
            for (int ni = 0; ni < 4; ++ni) {
                int n = wn * 64 + ni * 16 + (lane & 15);
                bf[ni] = *(const bf16x8*)((const char*)Bs + n * 128 + (cbyte ^ ((n & 7) << 4)));
            }
#pragma unroll
            for (int mi = 0; mi < 4; ++mi)
#pragma unroll
                for (int ni = 0; ni < 4; ++ni)
                    acc[mi][ni] = __builtin_amdgcn_mfma_f32_16x16x32_bf16(af[mi], bf[ni], acc[mi][ni], 0, 0, 0);
        }
        __syncthreads();
    }

    // epilogue. C/D: col = lane&15, row = (lane>>4)*4 + r
    const int colb = n0 + wn * 64 + (lane & 15);
    const int rowb = m0 + wm * 64 + (lane >> 4) * 4;
#pragma unroll
    for (int ni = 0; ni < 4; ++ni) {
        const int n = colb + ni * 16;
        const float bn = bias[n];
#pragma unroll
        for (int mi = 0; mi < 4; ++mi) {
#pragma unroll
            for (int r = 0; r < 4; ++r) {
                int m = rowb + mi * 16 + r;
                if (MODE == 0) {
                    int b = m / 196, s = 1 + m % 196;
                    out[((b * SEQL) + s) * HD + n] = acc[mi][ni][r] + bn + pos[s * HD + n];
                } else {
                    if (m < Mtot) {
                        float* p = &out[(size_t)m * HD + n];
                        *p = *p + fmaxf(acc[mi][ni][r] + bn, 0.f);
                    }
                }
            }
        }
    }
}

// ---------------- 2D LayerNorm stats (mean, rsigma) per image ----------------
__global__ void k_lnstats(const float* __restrict__ buf, float* __restrict__ stats, int which) {
    int b = blockIdx.x;
    const float* p = buf + (size_t)b * SEQL * HD;
    float s = 0.f, s2 = 0.f;
    const int NV = SEQL * HD / 4;   // 37824
    for (int i = threadIdx.x; i < NV; i += 256) {
        float4 v = ((const float4*)p)[i];
        s += v.x + v.y + v.z + v.w;
        s2 += v.x * v.x + v.y * v.y + v.z * v.z + v.w * v.w;
    }
    __shared__ float rs[8], rs2[8];
#pragma unroll
    for (int off = 32; off > 0; off >>= 1) {
        s += __shfl_down(s, off);
        s2 += __shfl_down(s2, off);
    }
    int lane = threadIdx.x & 63, w = threadIdx.x >> 6;
    if (lane == 0) { rs[w] = s; rs2[w] = s2; }
    __syncthreads();
    if (threadIdx.x == 0) {
        float S = 0.f, S2 = 0.f;
        for (int i = 0; i < 4; ++i) { S += rs[i]; S2 += rs2[i]; }
        const float inv_n = 1.0f / (float)(SEQL * HD);
        float mu = S * inv_n;
        float var = S2 * inv_n - mu * mu;
        stats[which * 128 + b * 2] = mu;
        stats[which * 128 + b * 2 + 1] = rsqrtf(var + 1e-5f);
    }
}

// ---------------- QKV projections (LN1 fused on load) ----------------
__launch_bounds__(256)
__global__ void k_qkv(const float* __restrict__ tok, const float* __restrict__ stats,
                      const float* __restrict__ g1, const float* __restrict__ b1,
                      const float* __restrict__ Wq, const float* __restrict__ bq,
                      const float* __restrict__ Wk, const float* __restrict__ bk,
                      const float* __restrict__ Wv, const float* __restrict__ bv,
                      float* __restrict__ q, float* __restrict__ k, float* __restrict__ v) {
    const int h = blockIdx.x, pj = blockIdx.y, b = blockIdx.z;
    __shared__ float Ws[64][68];    // [d][e]
    __shared__ float Xs[32][260];   // [d-chunk][s]
    const int tid = threadIdx.x;
    const int sg = tid >> 3, eg = tid & 7;

    const float* W  = (pj == 0) ? Wq : (pj == 1) ? Wk : Wv;
    const float* bp = (pj == 0) ? bq : (pj == 1) ? bk : bv;
    float* dst      = (pj == 0) ? q  : (pj == 1) ? k  : v;

#pragma unroll
    for (int l = 0; l < 4; ++l) {
        int ii = tid + l * 256;
        int d = ii >> 4, eq = ii & 15;
        *(float4*)&Ws[d][eq * 4] = *(const float4*)&W[(h * 64 + d) * 64 + eq * 4];
    }
    const float mu = stats[b * 2], rsg = stats[b * 2 + 1];
    const long base = (long)(b * 12 + h) * SEQL * 64;

    float acc[8][8];
#pragma unroll
    for (int i = 0; i < 8; ++i)
#pragma unroll
        for (int j = 0; j < 8; ++j) acc[i][j] = 0.f;

    for (int kc = 0; kc < 2; ++kc) {
        __syncthreads();
#pragma unroll
        for (int l = 0; l < 8; ++l) {
            int ii = tid + l * 256;
            int s = ii >> 3, dq = ii & 7;
            float4 xv = {0.f, 0.f, 0.f, 0.f};
            if (s < SEQL) {
                int off = (b * SEQL + s) * HD + h * 64 + kc * 32 + dq * 4;
                int loff = s * HD + h * 64 + kc * 32 + dq * 4;
                float4 t4 = *(const float4*)&tok[off];
                float4 g4 = *(const float4*)&g1[loff];
                float4 bb4 = *(const float4*)&b1[loff];
                xv.x = (t4.x - mu) * rsg * g4.x + bb4.x;
                xv.y = (t4.y - mu) * rsg * g4.y + bb4.y;
                xv.z = (t4.z - mu) * rsg * g4.z + bb4.z;
                xv.w = (t4.w - mu) * rsg * g4.w + bb4.w;
            }
            Xs[dq * 4 + 0][s] = xv.x;
            Xs[dq * 4 + 1][s] = xv.y;
            Xs[dq * 4 + 2][s] = xv.z;
            Xs[dq * 4 + 3][s] = xv.w;
        }
        __syncthreads();
#pragma unroll
        for (int d = 0; d < 32; ++d) {
            float a[8], w[8];
            *(float4*)&a[0] = *(float4*)&Xs[d][sg * 8];
            *(float4*)&a[4] = *(float4*)&Xs[d][sg * 8 + 4];
            *(float4*)&w[0] = *(float4*)&Ws[kc * 32 + d][eg * 8];
            *(float4*)&w[4] = *(float4*)&Ws[kc * 32 + d][eg * 8 + 4];
#pragma unroll
            for (int i = 0; i < 8; ++i)
#pragma unroll
                for (int j = 0; j < 8; ++j) acc[i][j] += a[i] * w[j];
        }
    }
    float4 bias0 = *(const float4*)&bp[h * 64 + eg * 8];
    float4 bias1 = *(const float4*)&bp[h * 64 + eg * 8 + 4];
#pragma unroll
    for (int i = 0; i < 8; ++i) {
        int s = sg * 8 + i;
        if (s < SEQL) {
            float4 o0, o1;
            o0.x = acc[i][0] + bias0.x;
            o0.y = acc[i][1] + bias0.y;
            o0.z = acc[i][2] + bias0.z;
            o0.w = acc[i][3] + bias0.w;
            o1.x = acc[i][4] + bias1.x;
            o1.y = acc[i][5] + bias1.y;
            o1.z = acc[i][6] + bias1.z;
            o1.w = acc[i][7] + bias1.w;
            *(float4*)&dst[base + (long)s * 64 + eg * 8] = o0;
            *(float4*)&dst[base + (long)s * 64 + eg * 8 + 4] = o1;
        }
    }
}

// ---------------- flash attention + residual ----------------
__launch_bounds__(256)
__global__ void k_attn(const float* __restrict__ q, const float* __restrict__ k,
                       const float* __restrict__ v, const float* __restrict__ tok,
                       float* __restrict__ out) {
    const int qt = blockIdx.x, h = blockIdx.y, b = blockIdx.z;
    __shared__ float Qs[64][68];
    __shared__ float KVs[64][68];
    __shared__ float Ps[64][68];
    const int tid = threadIdx.x, tx = tid & 15, ty = tid >> 4;
    const long base = (long)(b * 12 + h) * SEQL * 64;
    const int r0 = qt * 64;

#pragma unroll
    for (int l = 0; l < 4; ++l) {
        int ii = tid + l * 256;
        int r = ii >> 4, dq = ii & 15;
        float4 qv = {0.f, 0.f, 0.f, 0.f};
        if (r0 + r < SEQL) qv = *(const float4*)&q[base + (long)(r0 + r) * 64 + dq * 4];
        Qs[dq * 4 + 0][r] = qv.x;
        Qs[dq * 4 + 1][r] = qv.y;
        Qs[dq * 4 + 2][r] = qv.z;
        Qs[dq * 4 + 3][r] = qv.w;
    }

    float m_i[4], l_i[4], acc[4][4];
#pragma unroll
    for (int i = 0; i < 4; ++i) {
        m_i[i] = -INFINITY;
        l_i[i] = 0.f;
#pragma unroll
        for (int j = 0; j < 4; ++j) acc[i][j] = 0.f;
    }

    for (int tt = 0; tt < 4; ++tt) {
        const int t0 = tt * 64;
        __syncthreads();
#pragma unroll
        for (int l = 0; l < 4; ++l) {
            int ii = tid + l * 256;
            int t = ii >> 4, dq = ii & 15;
            float4 kv = {0.f, 0.f, 0.f, 0.f};
            if (t0 + t < SEQL) kv = *(const float4*)&k[base + (long)(t0 + t) * 64 + dq * 4];
            KVs[dq * 4 + 0][t] = kv.x;
            KVs[dq * 4 + 1][t] = kv.y;
            KVs[dq * 4 + 2][t] = kv.z;
            KVs[dq * 4 + 3][t] = kv.w;
        }
        __syncthreads();

        float sa[4][4];
#pragma unroll
        for (int i = 0; i < 4; ++i)
#pragma unroll
            for (int j = 0; j < 4; ++j) sa[i][j] = 0.f;
#pragma unroll
        for (int d = 0; d < 64; ++d) {
            float4 a4 = *(float4*)&Qs[d][ty * 4];
            float4 b4 = *(float4*)&KVs[d][tx * 4];
            float a[4] = {a4.x, a4.y, a4.z, a4.w};
            float bb[4] = {b4.x, b4.y, b4.z, b4.w};
#pragma unroll
            for (int i = 0; i < 4; ++i)
#pragma unroll
                for (int j = 0; j < 4; ++j) sa[i][j] += a[i] * bb[j];
        }

        float pr[4][4];
#pragma unroll
        for (int i = 0; i < 4; ++i) {
            float mt = -INFINITY;
#pragma unroll
            for (int j = 0; j < 4; ++j) {
                float sv = sa[i][j] * 0.125f;
                if (t0 + tx * 4 + j >= SEQL) sv = -1e30f;
                sa[i][j] = sv;
                mt = fmaxf(mt, sv);
            }
            mt = fmaxf(mt, __shfl_xor(mt, 1));
            mt = fmaxf(mt, __shfl_xor(mt, 2));
            mt = fmaxf(mt, __shfl_xor(mt, 4));
            mt = fmaxf(mt, __shfl_xor(mt, 8));
            float mn = fmaxf(m_i[i], mt);
            float alpha = __expf(m_i[i] - mn);
            float rsum = 0.f;
#pragma unroll
            for (int j = 0; j < 4; ++j) {
                float p = __expf(sa[i][j] - mn);
                pr[i][j] = p;
                rsum += p;
            }
            rsum += __shfl_xor(rsum, 1);
            rsum += __shfl_xor(rsum, 2);
            rsum += __shfl_xor(rsum, 4);
            rsum += __shfl_xor(rsum, 8);
            l_i[i] = l_i[i] * alpha + rsum;
            m_i[i] = mn;
#pragma unroll
            for (int j = 0; j < 4; ++j) acc[i][j] *= alpha;
#pragma unroll
            for (int j = 0; j < 4; ++j) Ps[tx * 4 + j][ty * 4 + i] = pr[i][j];
        }
        __syncthreads();
#pragma unroll
        for (int l = 0; l < 4; ++l) {
            int ii = tid + l * 256;
            int t = ii >> 4, dq = ii & 15;
            float4 vv = {0.f, 0.f, 0.f, 0.f};
            if (t0 + t < SEQL) vv = *(const float4*)&v[base + (long)(t0 + t) * 64 + dq * 4];
            *(float4*)&KVs[t][dq * 4] = vv;
        }
        __syncthreads();
#pragma unroll
        for (int t = 0; t < 64; ++t) {
            float4 a4 = *(float4*)&Ps[t][ty * 4];
            float4 b4 = *(float4*)&KVs[t][tx * 4];
            float a[4] = {a4.x, a4.y, a4.z, a4.w};
            float bb[4] = {b4.x, b4.y, b4.z, b4.w};
#pragma unroll
            for (int i = 0; i < 4; ++i)
#pragma unroll
                for (int j = 0; j < 4; ++j) acc[i][j] += a[i] * bb[j];
        }
    }
#pragma unroll
    for (int i = 0; i < 4; ++i) {
        int r = r0 + ty * 4 + i;
        if (r < SEQL) {
            float inv = 1.0f / l_i[i];
            int off = (b * SEQL + r) * HD + h * 64 + tx * 4;
            float4 t4 = *(const float4*)&tok[off];
            float4 o;
            o.x = acc[i][0] * inv + t4.x;
            o.y = acc[i][1] * inv + t4.y;
            o.z = acc[i][2] * inv + t4.z;
            o.w = acc[i][3] * inv + t4.w;
            *(float4*)&out[off] = o;
        }
    }
}

// ---------------- LN2 apply -> bf16 A for encoder GEMM ----------------
__global__ void k_ln2apply(const float* __restrict__ outb, const float* __restrict__ stats,
                           const float* __restrict__ g2, const float* __restrict__ b2,
                           ushort_t* __restrict__ x) {
    int i = blockIdx.x * 256 + threadIdx.x;
    if (i >= BATCH * SEQL * HD / 4) return;
    int e4 = i * 4;
    int m = e4 / HD, kk = e4 % HD;
    int b = m / SEQL, s = m % SEQL;
    float mu = stats[128 + b * 2], rsg = stats[128 + b * 2 + 1];
    float4 t = *(const float4*)&outb[e4];
    float4 g = *(const float4*)&g2[s * HD + kk];
    float4 bb = *(const float4*)&b2[s * HD + kk];
    ushort4 o;
    o.x = f2bf((t.x - mu) * rsg * g.x + bb.x);
    o.y = f2bf((t.y - mu) * rsg * g.y + bb.y);
    o.z = f2bf((t.z - mu) * rsg * g.z + bb.z);
    o.w = f2bf((t.w - mu) * rsg * g.w + bb.w);
    *(ushort4*)&x[e4] = o;
}

// ---------------- classifier head + softmax ----------------
__launch_bounds__(256)
__global__ void k_head(const float* __restrict__ out, const float* __restrict__ Wo,
                       const float* __restrict__ bo, float* __restrict__ dout) {
    const int b = blockIdx.x, tid = threadIdx.x;
    __shared__ float cls[768];
    __shared__ float red[256];
    for (int i = tid; i < 192; i += 256)
        *(float4*)&cls[i * 4] = *(const float4*)&out[(b * SEQL) * HD + i * 4];
    __syncthreads();

    const int o0 = tid * 4;
    const bool ok = (o0 < OUTD);
    float4 acc = {0.f, 0.f, 0.f, 0.f};
    if (ok) {
        acc = *(const float4*)&bo[o0];
        for (int e = 0; e < 768; ++e) {
            float c = cls[e];
            float4 w = *(const float4*)&Wo[e * OUTD + o0];
            acc.x += c * w.x;
            acc.y += c * w.y;
            acc.z += c * w.z;
            acc.w += c * w.w;
        }
    }
    float mx = ok ? fmaxf(fmaxf(acc.x, acc.y), fmaxf(acc.z, acc.w)) : -INFINITY;
    red[tid] = mx;
    __syncthreads();
    for (int s = 128; s > 0; s >>= 1) {
        if (tid < s) red[tid] = fmaxf(red[tid], red[tid + s]);
        __syncthreads();
    }
    float M = red[0];
    __syncthreads();
    float4 p = {0.f, 0.f, 0.f, 0.f};
    float ls = 0.f;
    if (ok) {
        p.x = expf(acc.x - M);
        p.y = expf(acc.y - M);
        p.z = expf(acc.z - M);
        p.w = expf(acc.w - M);
        ls = p.x + p.y + p.z + p.w;
    }
    red[tid] = ls;
    __syncthreads();
    for (int s = 128; s > 0; s >>= 1) {
        if (tid < s) red[tid] += red[tid + s];
        __syncthreads();
    }
    float inv = 1.0f / red[0];
    if (ok) {
        p.x *= inv; p.y *= inv; p.z *= inv; p.w *= inv;
        *(float4*)&dout[b * OUTD + o0] = p;
    }
}

extern "C" void kernel_launch(void* const* d_in, const int* in_sizes, int n_in,
                              void* d_out, int out_size, void* d_ws, size_t ws_size,
                              hipStream_t stream) {
    const float* images  = (const float*)d_in[0];
    const float* W_map   = (const float*)d_in[1];
    const float* b_map   = (const float*)d_in[2];
    const float* cls_tok = (const float*)d_in[3];
    const float* ln1_g   = (const float*)d_in[4];
    const float* ln1_b   = (const float*)d_in[5];
    const float* Wq      = (const float*)d_in[6];
    const float* bq      = (const float*)d_in[7];
    const float* Wk      = (const float*)d_in[8];
    const float* bk      = (const float*)d_in[9];
    const float* Wv      = (const float*)d_in[10];
    const float* bv      = (const float*)d_in[11];
    const float* ln2_g   = (const float*)d_in[12];
    const float* ln2_b   = (const float*)d_in[13];
    const float* W_enc   = (const float*)d_in[14];
    const float* b_enc   = (const float*)d_in[15];
    const float* W_out   = (const float*)d_in[16];
    const float* b_out   = (const float*)d_in[17];

    float* ws = (float*)d_ws;
    const size_t BIG = (size_t)BATCH * SEQL * HD;   // 9,682,944
    float* pos   = ws;
    float* tok   = ws + 151552;
    float* outb  = tok + BIG;
    float* qb    = outb + BIG;
    float* kb    = qb + BIG;
    float* vb    = kb + BIG;
    float* stats = vb + BIG;                        // 256 floats

    // overlays (regions dead at the time of use):
    ushort_t* Ae  = (ushort_t*)kb;                  // patches bf16 [12544][768] (dead before k_qkv writes kb)
    ushort_t* WmT = (ushort_t*)(kb + 5000000);      // W_map^T bf16 (dead before k_qkv)
    ushort_t* Ae2 = (ushort_t*)vb;                  // LN2-out bf16 [<=12672][768] (vb dead after attn)
    ushort_t* WeT = (ushort_t*)kb;                  // W_enc^T bf16 (kb dead after attn)

    k_pos<<<591, 256, 0, stream>>>(pos);
    k_cls<<<192, 256, 0, stream>>>(cls_tok, pos, tok);
    k_cvtW<<<576, 256, 0, stream>>>(W_map, WmT);
    k_prep_patches<<<9408, 256, 0, stream>>>(images, Ae);
    k_gemm_bf16<0><<<dim3(98, 6), 256, 0, stream>>>(Ae, WmT, b_map, pos, tok, 12544);
    k_lnstats<<<64, 256, 0, stream>>>(tok, stats, 0);
    k_qkv<<<dim3(12, 3, 64), 256, 0, stream>>>(tok, stats, ln1_g, ln1_b, Wq, bq, Wk, bk, Wv, bv, qb, kb, vb);
    k_attn<<<dim3(4, 12, 64), 256, 0, stream>>>(qb, kb, vb, tok, outb);
    k_cvtW<<<576, 256, 0, stream>>>(W_enc, WeT);
    k_lnstats<<<64, 256, 0, stream>>>(outb, stats, 1);
    k_ln2apply<<<9456, 256, 0, stream>>>(outb, stats, ln2_g, ln2_b, Ae2);
    k_gemm_bf16<1><<<dim3(99, 6), 256, 0, stream>>>(Ae2, WeT, b_enc, pos, outb, 12608);
    k_head<<<64, 256, 0, stream>>>(outb, W_out, b_out, (float*)d_out);
}

// Round 4
// 470.270 us; speedup vs baseline: 3.4364x; 1.3711x over previous
//
#include <hip/hip_runtime.h>
#include <math.h>

#define SEQL 197
#define HD 768
#define NH 12
#define DHD 64
#define BATCH 64
#define OUTD 1000

typedef unsigned short ushort_t;
typedef __attribute__((ext_vector_type(8))) short bf16x8;
typedef __attribute__((ext_vector_type(4))) float f32x4;

static __device__ __forceinline__ unsigned short f2bf(float f) {
    union { float f; unsigned u; } v; v.f = f;
    unsigned r = v.u + 0x7fff + ((v.u >> 16) & 1);
    return (unsigned short)(r >> 16);
}

static __device__ __forceinline__ void gload16(const ushort_t* g, ushort_t* l) {
    __builtin_amdgcn_global_load_lds(
        (const __attribute__((address_space(1))) unsigned int*)g,
        (__attribute__((address_space(3))) unsigned int*)l, 16, 0, 0);
}

// ---------------- positional embedding table ----------------
__global__ void k_pos(float* __restrict__ pos) {
    int i = blockIdx.x * 256 + threadIdx.x;
    if (i >= SEQL * HD) return;
    int s = i / HD, d = i % HD;
    float f = (float)(d & ~1);
    float r = powf(10000.0f, -f / (float)HD);
    float a = (float)s * r;
    pos[i] = (d & 1) ? cosf(a) : sinf(a);
}

// ---------------- cls row of tokens ----------------
__global__ void k_cls(const float* __restrict__ cls_tok, const float* __restrict__ pos,
                      float* __restrict__ tok) {
    int i = blockIdx.x * 256 + threadIdx.x;
    if (i >= BATCH * HD) return;
    int b = i / HD, e = i % HD;
    tok[(b * SEQL) * HD + e] = cls_tok[e] + pos[e];
}

// ---------------- W (f32 [K][N]) -> W^T bf16 [N][K], K=N=768 ----------------
__global__ void k_cvtW(const float* __restrict__ W, ushort_t* __restrict__ WT) {
    int idx = blockIdx.x * 256 + threadIdx.x;       // 0 .. 768*192
    if (idx >= 768 * 192) return;
    int k = idx / 192, nq = idx % 192;
    float4 w = *(const float4*)&W[k * 768 + nq * 4];
    WT[(nq * 4 + 0) * 768 + k] = f2bf(w.x);
    WT[(nq * 4 + 1) * 768 + k] = f2bf(w.y);
    WT[(nq * 4 + 2) * 768 + k] = f2bf(w.z);
    WT[(nq * 4 + 3) * 768 + k] = f2bf(w.w);
}

// ---------------- gather patches -> bf16 A [12544][768] ----------------
__global__ void k_prep_patches(const float* __restrict__ img, ushort_t* __restrict__ Ae) {
    int idx = blockIdx.x * 256 + threadIdx.x;       // 0 .. 12544*192
    int m = idx / 192, kq = idx % 192;
    int k0 = kq * 4;
    int c = k0 >> 8, rem = k0 & 255, ir = rem >> 4, jc = rem & 15;
    int b = m / 196, pi = m % 196;
    int pr = pi / 14, pc = pi % 14;
    float4 v = *(const float4*)&img[((b * 3 + c) * 224 + pr * 16 + ir) * 224 + pc * 16 + jc];
    ushort4 o;
    o.x = f2bf(v.x); o.y = f2bf(v.y); o.z = f2bf(v.z); o.w = f2bf(v.w);
    *(ushort4*)&Ae[m * 768 + k0] = o;
}

// ---------------- bf16 MFMA GEMM, 128x128 tile, BK=64, 4 waves ----------------
template <int MODE>
__launch_bounds__(256)
__global__ void k_gemm_bf16(const ushort_t* __restrict__ A, const ushort_t* __restrict__ Bt,
                            const float* __restrict__ bias, const float* __restrict__ pos,
                            float* __restrict__ out, int Mtot) {
    __shared__ ushort_t As[128 * 64];
    __shared__ ushort_t Bs[128 * 64];
    const int m0 = blockIdx.x * 128;
    const int n0 = blockIdx.y * 128;
    const int tid = threadIdx.x;
    const int lane = tid & 63, wave = tid >> 6;
    const int wm = wave >> 1, wn = wave & 1;

    f32x4 acc[4][4];
#pragma unroll
    for (int i = 0; i < 4; ++i)
#pragma unroll
        for (int j = 0; j < 4; ++j)
#pragma unroll
            for (int r = 0; r < 4; ++r) acc[i][j][r] = 0.f;

    for (int kt = 0; kt < 12; ++kt) {
        const int k0 = kt * 64;
#pragma unroll
        for (int t = 0; t < 4; ++t) {
            int c = (wave << 2) | t;
            int o = c * 1024 + lane * 16;
            int row = o >> 7;
            int inner = o & 127;
            int col = (inner ^ ((row & 7) << 4)) >> 1;
            gload16(&A[(size_t)(m0 + row) * 768 + k0 + col], &As[c * 512]);
            gload16(&Bt[(size_t)(n0 + row) * 768 + k0 + col], &Bs[c * 512]);
        }
        __syncthreads();
#pragma unroll
        for (int ks = 0; ks < 2; ++ks) {
            const int cbyte = ks * 64 + (lane >> 4) * 16;
            bf16x8 af[4], bf[4];
#pragma unroll
            for (int mi = 0; mi < 4; ++mi) {
                int row = wm * 64 + mi * 16 + (lane & 15);
                af[mi] = *(const bf16x8*)((const char*)As + row * 128 + (cbyte ^ ((row & 7) << 4)));
            }
#pragma unroll
            for (int ni = 0; ni < 4; ++ni) {
                int n = wn * 64 + ni * 16 + (lane & 15);
                bf[ni] = *(const bf16x8*)((const char*)Bs + n * 128 + (cbyte ^ ((n & 7) << 4)));
            }
#pragma unroll
            for (int mi = 0; mi < 4; ++mi)
#pragma unroll
                for (int ni = 0; ni < 4; ++ni)
                    acc[mi][ni] = __builtin_amdgcn_mfma_f32_16x16x32_bf16(af[mi], bf[ni], acc[mi][ni], 0, 0, 0);
        }
        __syncthreads();
    }

    const int colb = n0 + wn * 64 + (lane & 15);
    const int rowb = m0 + wm * 64 + (lane >> 4) * 4;
#pragma unroll
    for (int ni = 0; ni < 4; ++ni) {
        const int n = colb + ni * 16;
        const float bn = bias[n];
#pragma unroll
        for (int mi = 0; mi < 4; ++mi) {
#pragma unroll
            for (int r = 0; r < 4; ++r) {
                int m = rowb + mi * 16 + r;
                if (MODE == 0) {
                    int b = m / 196, s = 1 + m % 196;
                    out[((b * SEQL) + s) * HD + n] = acc[mi][ni][r] + bn + pos[s * HD + n];
                } else {
                    if (m < Mtot) {
                        float* p = &out[(size_t)m * HD + n];
                        *p = *p + fmaxf(acc[mi][ni][r] + bn, 0.f);
                    }
                }
            }
        }
    }
}

// ---------------- 2D LayerNorm stats (mean, rsigma) per image ----------------
__global__ void k_lnstats(const float* __restrict__ buf, float* __restrict__ stats, int which) {
    int b = blockIdx.x;
    const float* p = buf + (size_t)b * SEQL * HD;
    float s = 0.f, s2 = 0.f;
    const int NV = SEQL * HD / 4;
    for (int i = threadIdx.x; i < NV; i += 256) {
        float4 v = ((const float4*)p)[i];
        s += v.x + v.y + v.z + v.w;
        s2 += v.x * v.x + v.y * v.y + v.z * v.z + v.w * v.w;
    }
    __shared__ float rs[8], rs2[8];
#pragma unroll
    for (int off = 32; off > 0; off >>= 1) {
        s += __shfl_down(s, off);
        s2 += __shfl_down(s2, off);
    }
    int lane = threadIdx.x & 63, w = threadIdx.x >> 6;
    if (lane == 0) { rs[w] = s; rs2[w] = s2; }
    __syncthreads();
    if (threadIdx.x == 0) {
        float S = 0.f, S2 = 0.f;
        for (int i = 0; i < 4; ++i) { S += rs[i]; S2 += rs2[i]; }
        const float inv_n = 1.0f / (float)(SEQL * HD);
        float mu = S * inv_n;
        float var = S2 * inv_n - mu * mu;
        stats[which * 128 + b * 2] = mu;
        stats[which * 128 + b * 2 + 1] = rsqrtf(var + 1e-5f);
    }
}

// ---------------- QKV projections (LN1 fused on load), bf16 outputs ----------------
// q,k: bf16 [bh][256][64] (rows >=197 zeroed). v: bf16 TRANSPOSED [bh][64][256] (pad zeroed).
__launch_bounds__(256)
__global__ void k_qkv(const float* __restrict__ tok, const float* __restrict__ stats,
                      const float* __restrict__ g1, const float* __restrict__ b1,
                      const float* __restrict__ Wq, const float* __restrict__ bq,
                      const float* __restrict__ Wk, const float* __restrict__ bk,
                      const float* __restrict__ Wv, const float* __restrict__ bv,
                      ushort_t* __restrict__ q16, ushort_t* __restrict__ k16,
                      ushort_t* __restrict__ vt16) {
    const int h = blockIdx.x, pj = blockIdx.y, b = blockIdx.z;
    __shared__ float Ws[64][68];
    __shared__ float Xs[32][260];
    const int tid = threadIdx.x;
    const int sg = tid >> 3, eg = tid & 7;

    const float* W  = (pj == 0) ? Wq : (pj == 1) ? Wk : Wv;
    const float* bp = (pj == 0) ? bq : (pj == 1) ? bk : bv;

#pragma unroll
    for (int l = 0; l < 4; ++l) {
        int ii = tid + l * 256;
        int d = ii >> 4, eq = ii & 15;
        *(float4*)&Ws[d][eq * 4] = *(const float4*)&W[(h * 64 + d) * 64 + eq * 4];
    }
    const float mu = stats[b * 2], rsg = stats[b * 2 + 1];

    float acc[8][8];
#pragma unroll
    for (int i = 0; i < 8; ++i)
#pragma unroll
        for (int j = 0; j < 8; ++j) acc[i][j] = 0.f;

    for (int kc = 0; kc < 2; ++kc) {
        __syncthreads();
#pragma unroll
        for (int l = 0; l < 8; ++l) {
            int ii = tid + l * 256;
            int s = ii >> 3, dq = ii & 7;
            float4 xv = {0.f, 0.f, 0.f, 0.f};
            if (s < SEQL) {
                int off = (b * SEQL + s) * HD + h * 64 + kc * 32 + dq * 4;
                int loff = s * HD + h * 64 + kc * 32 + dq * 4;
                float4 t4 = *(const float4*)&tok[off];
                float4 g4 = *(const float4*)&g1[loff];
                float4 bb4 = *(const float4*)&b1[loff];
                xv.x = (t4.x - mu) * rsg * g4.x + bb4.x;
                xv.y = (t4.y - mu) * rsg * g4.y + bb4.y;
                xv.z = (t4.z - mu) * rsg * g4.z + bb4.z;
                xv.w = (t4.w - mu) * rsg * g4.w + bb4.w;
            }
            Xs[dq * 4 + 0][s] = xv.x;
            Xs[dq * 4 + 1][s] = xv.y;
            Xs[dq * 4 + 2][s] = xv.z;
            Xs[dq * 4 + 3][s] = xv.w;
        }
        __syncthreads();
#pragma unroll
        for (int d = 0; d < 32; ++d) {
            float a[8], w[8];
            *(float4*)&a[0] = *(float4*)&Xs[d][sg * 8];
            *(float4*)&a[4] = *(float4*)&Xs[d][sg * 8 + 4];
            *(float4*)&w[0] = *(float4*)&Ws[kc * 32 + d][eg * 8];
            *(float4*)&w[4] = *(float4*)&Ws[kc * 32 + d][eg * 8 + 4];
#pragma unroll
            for (int i = 0; i < 8; ++i)
#pragma unroll
                for (int j = 0; j < 8; ++j) acc[i][j] += a[i] * w[j];
        }
    }
    float bias[8];
    *(float4*)&bias[0] = *(const float4*)&bp[h * 64 + eg * 8];
    *(float4*)&bias[4] = *(const float4*)&bp[h * 64 + eg * 8 + 4];

    if (pj < 2) {
        ushort_t* dst = (pj == 0) ? q16 : k16;
        const size_t base = (size_t)(b * 12 + h) * 256 * 64;
#pragma unroll
        for (int i = 0; i < 8; ++i) {
            int s = sg * 8 + i;
            ushort4 o0, o1;
            if (s < SEQL) {
                o0.x = f2bf(acc[i][0] + bias[0]);
                o0.y = f2bf(acc[i][1] + bias[1]);
                o0.z = f2bf(acc[i][2] + bias[2]);
                o0.w = f2bf(acc[i][3] + bias[3]);
                o1.x = f2bf(acc[i][4] + bias[4]);
                o1.y = f2bf(acc[i][5] + bias[5]);
                o1.z = f2bf(acc[i][6] + bias[6]);
                o1.w = f2bf(acc[i][7] + bias[7]);
            } else {
                o0.x = o0.y = o0.z = o0.w = 0;
                o1.x = o1.y = o1.z = o1.w = 0;
            }
            *(ushort4*)&dst[base + (size_t)s * 64 + eg * 8] = o0;
            *(ushort4*)&dst[base + (size_t)s * 64 + eg * 8 + 4] = o1;
        }
    } else {
        const size_t vb = (size_t)(b * 12 + h) * 64 * 256;
#pragma unroll
        for (int i = 0; i < 8; ++i) {
            int s = sg * 8 + i;
#pragma unroll
            for (int j = 0; j < 8; ++j) {
                ushort_t val = (s < SEQL) ? f2bf(acc[i][j] + bias[j]) : (ushort_t)0;
                vt16[vb + (size_t)(eg * 8 + j) * 256 + s] = val;
            }
        }
    }
}

// ---------------- MFMA flash attention + residual ----------------
// 8 waves / block; wave owns 32 q-rows. K/V read direct from global (L2-resident).
__launch_bounds__(512)
__global__ void k_attn_mfma(const ushort_t* __restrict__ q, const ushort_t* __restrict__ k,
                            const ushort_t* __restrict__ vt, const float* __restrict__ tok,
                            float* __restrict__ out) {
    const int h = blockIdx.x, b = blockIdx.y;
    const int tid = threadIdx.x;
    const int wave = tid >> 6, lane = tid & 63;
    const int l16 = lane & 15, l4 = lane >> 4;
    __shared__ ushort_t Ps[8][32 * 72];            // per-wave P tile [32 q][72 t]

    const size_t qkbase = (size_t)(b * 12 + h) * 256 * 64;
    const size_t vbase  = (size_t)(b * 12 + h) * 64 * 256;
    const int r0 = wave * 32;

    // Q A-fragments (held in registers for all 4 KV tiles)
    bf16x8 qa[2][2];
#pragma unroll
    for (int mi = 0; mi < 2; ++mi)
#pragma unroll
        for (int kk = 0; kk < 2; ++kk)
            qa[mi][kk] = *(const bf16x8*)&q[qkbase + (size_t)(r0 + mi * 16 + l16) * 64 + kk * 32 + l4 * 8];

    f32x4 oacc[2][4];
    float m_s[2][4], l_s[2][4];
#pragma unroll
    for (int mi = 0; mi < 2; ++mi) {
#pragma unroll
        for (int r = 0; r < 4; ++r) {
            m_s[mi][r] = -INFINITY;
            l_s[mi][r] = 0.f;
        }
#pragma unroll
        for (int ne = 0; ne < 4; ++ne)
#pragma unroll
            for (int r = 0; r < 4; ++r) oacc[mi][ne][r] = 0.f;
    }

    ushort_t* myP = &Ps[wave][0];

    for (int tt = 0; tt < 4; ++tt) {
        const int t0 = tt * 64;
        // K B-fragments (direct global, L2-hit)
        bf16x8 kf[4][2];
#pragma unroll
        for (int ni = 0; ni < 4; ++ni)
#pragma unroll
            for (int kk = 0; kk < 2; ++kk)
                kf[ni][kk] = *(const bf16x8*)&k[qkbase + (size_t)(t0 + ni * 16 + l16) * 64 + kk * 32 + l4 * 8];

        // scores = Q @ K^T : C cols (lane&15) = t, rows = q
        f32x4 sa[2][4];
#pragma unroll
        for (int mi = 0; mi < 2; ++mi)
#pragma unroll
            for (int ni = 0; ni < 4; ++ni) {
                f32x4 z;
                z[0] = 0.f; z[1] = 0.f; z[2] = 0.f; z[3] = 0.f;
                z = __builtin_amdgcn_mfma_f32_16x16x32_bf16(qa[mi][0], kf[ni][0], z, 0, 0, 0);
                sa[mi][ni] = __builtin_amdgcn_mfma_f32_16x16x32_bf16(qa[mi][1], kf[ni][1], z, 0, 0, 0);
            }

        // online softmax (per q-row, 16 lanes share a row-set)
#pragma unroll
        for (int mi = 0; mi < 2; ++mi) {
#pragma unroll
            for (int r = 0; r < 4; ++r) {
                float sv[4];
                float mt = -INFINITY;
#pragma unroll
                for (int ni = 0; ni < 4; ++ni) {
                    float s = sa[mi][ni][r] * 0.125f;
                    if (t0 + ni * 16 + l16 >= SEQL) s = -1e30f;
                    sv[ni] = s;
                    mt = fmaxf(mt, s);
                }
                mt = fmaxf(mt, __shfl_xor(mt, 1));
                mt = fmaxf(mt, __shfl_xor(mt, 2));
                mt = fmaxf(mt, __shfl_xor(mt, 4));
                mt = fmaxf(mt, __shfl_xor(mt, 8));
                float mn = fmaxf(m_s[mi][r], mt);
                float alpha = __expf(m_s[mi][r] - mn);
                m_s[mi][r] = mn;
                float rsum = 0.f;
#pragma unroll
                for (int ni = 0; ni < 4; ++ni) {
                    float p = __expf(sv[ni] - mn);
                    rsum += p;
                    myP[(mi * 16 + l4 * 4 + r) * 72 + ni * 16 + l16] = f2bf(p);
                }
                rsum += __shfl_xor(rsum, 1);
                rsum += __shfl_xor(rsum, 2);
                rsum += __shfl_xor(rsum, 4);
                rsum += __shfl_xor(rsum, 8);
                l_s[mi][r] = l_s[mi][r] * alpha + rsum;
#pragma unroll
                for (int ne = 0; ne < 4; ++ne)
#pragma unroll
                    for (int rr = 0; rr < 1; ++rr) oacc[mi][ne][r] *= alpha;
            }
        }

        // PV: A = P (from own LDS tile), B = V^T rows = e (direct global)
        bf16x8 vf[4][2];
#pragma unroll
        for (int ne = 0; ne < 4; ++ne)
#pragma unroll
            for (int kk = 0; kk < 2; ++kk)
                vf[ne][kk] = *(const bf16x8*)&vt[vbase + (size_t)(ne * 16 + l16) * 256 + t0 + kk * 32 + l4 * 8];
        bf16x8 pa[2][2];
#pragma unroll
        for (int mi = 0; mi < 2; ++mi)
#pragma unroll
            for (int kk = 0; kk < 2; ++kk)
                pa[mi][kk] = *(const bf16x8*)&myP[(mi * 16 + l16) * 72 + kk * 32 + l4 * 8];
#pragma unroll
        for (int mi = 0; mi < 2; ++mi)
#pragma unroll
            for (int ne = 0; ne < 4; ++ne) {
                oacc[mi][ne] = __builtin_amdgcn_mfma_f32_16x16x32_bf16(pa[mi][0], vf[ne][0], oacc[mi][ne], 0, 0, 0);
                oacc[mi][ne] = __builtin_amdgcn_mfma_f32_16x16x32_bf16(pa[mi][1], vf[ne][1], oacc[mi][ne], 0, 0, 0);
            }
    }

    // epilogue: O/l + residual
#pragma unroll
    for (int mi = 0; mi < 2; ++mi) {
#pragma unroll
        for (int r = 0; r < 4; ++r) {
            int row = r0 + mi * 16 + l4 * 4 + r;
            if (row < SEQL) {
                float inv = 1.0f / l_s[mi][r];
                size_t off = ((size_t)(b * SEQL + row)) * HD + h * 64;
#pragma unroll
                for (int ne = 0; ne < 4; ++ne) {
                    int e = ne * 16 + l16;
                    out[off + e] = oacc[mi][ne][r] * inv + tok[off + e];
                }
            }
        }
    }
}

// ---------------- LN2 apply -> bf16 A for encoder GEMM ----------------
__global__ void k_ln2apply(const float* __restrict__ outb, const float* __restrict__ stats,
                           const float* __restrict__ g2, const float* __restrict__ b2,
                           ushort_t* __restrict__ x) {
    int i = blockIdx.x * 256 + threadIdx.x;
    if (i >= BATCH * SEQL * HD / 4) return;
    int e4 = i * 4;
    int m = e4 / HD, kk = e4 % HD;
    int b = m / SEQL, s = m % SEQL;
    float mu = stats[128 + b * 2], rsg = stats[128 + b * 2 + 1];
    float4 t = *(const float4*)&outb[e4];
    float4 g = *(const float4*)&g2[s * HD + kk];
    float4 bb = *(const float4*)&b2[s * HD + kk];
    ushort4 o;
    o.x = f2bf((t.x - mu) * rsg * g.x + bb.x);
    o.y = f2bf((t.y - mu) * rsg * g.y + bb.y);
    o.z = f2bf((t.z - mu) * rsg * g.z + bb.z);
    o.w = f2bf((t.w - mu) * rsg * g.w + bb.w);
    *(ushort4*)&x[e4] = o;
}

// ---------------- classifier head + softmax ----------------
__launch_bounds__(256)
__global__ void k_head(const float* __restrict__ out, const float* __restrict__ Wo,
                       const float* __restrict__ bo, float* __restrict__ dout) {
    const int b = blockIdx.x, tid = threadIdx.x;
    __shared__ float cls[768];
    __shared__ float red[256];
    for (int i = tid; i < 192; i += 256)
        *(float4*)&cls[i * 4] = *(const float4*)&out[(b * SEQL) * HD + i * 4];
    __syncthreads();

    const int o0 = tid * 4;
    const bool ok = (o0 < OUTD);
    float4 acc = {0.f, 0.f, 0.f, 0.f};
    if (ok) {
        acc = *(const float4*)&bo[o0];
        for (int e = 0; e < 768; ++e) {
            float c = cls[e];
            float4 w = *(const float4*)&Wo[e * OUTD + o0];
            acc.x += c * w.x;
            acc.y += c * w.y;
            acc.z += c * w.z;
            acc.w += c * w.w;
        }
    }
    float mx = ok ? fmaxf(fmaxf(acc.x, acc.y), fmaxf(acc.z, acc.w)) : -INFINITY;
    red[tid] = mx;
    __syncthreads();
    for (int s = 128; s > 0; s >>= 1) {
        if (tid < s) red[tid] = fmaxf(red[tid], red[tid + s]);
        __syncthreads();
    }
    float M = red[0];
    __syncthreads();
    float4 p = {0.f, 0.f, 0.f, 0.f};
    float ls = 0.f;
    if (ok) {
        p.x = expf(acc.x - M);
        p.y = expf(acc.y - M);
        p.z = expf(acc.z - M);
        p.w = expf(acc.w - M);
        ls = p.x + p.y + p.z + p.w;
    }
    red[tid] = ls;
    __syncthreads();
    for (int s = 128; s > 0; s >>= 1) {
        if (tid < s) red[tid] += red[tid + s];
        __syncthreads();
    }
    float inv = 1.0f / red[0];
    if (ok) {
        p.x *= inv; p.y *= inv; p.z *= inv; p.w *= inv;
        *(float4*)&dout[b * OUTD + o0] = p;
    }
}

extern "C" void kernel_launch(void* const* d_in, const int* in_sizes, int n_in,
                              void* d_out, int out_size, void* d_ws, size_t ws_size,
                              hipStream_t stream) {
    const float* images  = (const float*)d_in[0];
    const float* W_map   = (const float*)d_in[1];
    const float* b_map   = (const float*)d_in[2];
    const float* cls_tok = (const float*)d_in[3];
    const float* ln1_g   = (const float*)d_in[4];
    const float* ln1_b   = (const float*)d_in[5];
    const float* Wq      = (const float*)d_in[6];
    const float* bq      = (const float*)d_in[7];
    const float* Wk      = (const float*)d_in[8];
    const float* bk      = (const float*)d_in[9];
    const float* Wv      = (const float*)d_in[10];
    const float* bv      = (const float*)d_in[11];
    const float* ln2_g   = (const float*)d_in[12];
    const float* ln2_b   = (const float*)d_in[13];
    const float* W_enc   = (const float*)d_in[14];
    const float* b_enc   = (const float*)d_in[15];
    const float* W_out   = (const float*)d_in[16];
    const float* b_out   = (const float*)d_in[17];

    float* ws = (float*)d_ws;
    const size_t BIG = (size_t)BATCH * SEQL * HD;   // 9,682,944
    const size_t QKB = (size_t)BATCH * 12 * 256 * 64; // 12,582,912 bf16 elems per buffer

    float* pos   = ws;                         // 151,296 (+pad)
    float* tok   = ws + 151552;                // BIG f32
    float* outb  = tok + BIG;                  // BIG f32
    float* stats = outb + BIG;                 // 256 f32
    ushort_t* q16  = (ushort_t*)(stats + 256); // QKB bf16
    ushort_t* k16  = q16 + QKB;                // QKB bf16
    ushort_t* vt16 = k16 + QKB;                // QKB bf16 (transposed [bh][64][256])

    // overlays (dead at time of use):
    ushort_t* Ae  = q16;                       // patches bf16 [12544][768] (dead before k_qkv)
    ushort_t* WmT = k16;                       // W_map^T bf16 (dead before k_qkv)
    ushort_t* Ae2 = q16;                       // LN2-out bf16 (q16 dead after attn)
    ushort_t* WeT = k16;                       // W_enc^T bf16 (k16 dead after attn)

    k_pos<<<591, 256, 0, stream>>>(pos);
    k_cls<<<192, 256, 0, stream>>>(cls_tok, pos, tok);
    k_cvtW<<<576, 256, 0, stream>>>(W_map, WmT);
    k_prep_patches<<<9408, 256, 0, stream>>>(images, Ae);
    k_gemm_bf16<0><<<dim3(98, 6), 256, 0, stream>>>(Ae, WmT, b_map, pos, tok, 12544);
    k_lnstats<<<64, 256, 0, stream>>>(tok, stats, 0);
    k_qkv<<<dim3(12, 3, 64), 256, 0, stream>>>(tok, stats, ln1_g, ln1_b, Wq, bq, Wk, bk, Wv, bv, q16, k16, vt16);
    k_attn_mfma<<<dim3(12, 64), 512, 0, stream>>>(q16, k16, vt16, tok, outb);
    k_cvtW<<<576, 256, 0, stream>>>(W_enc, WeT);
    k_lnstats<<<64, 256, 0, stream>>>(outb, stats, 1);
    k_ln2apply<<<9456, 256, 0, stream>>>(outb, stats, ln2_g, ln2_b, Ae2);
    k_gemm_bf16<1><<<dim3(99, 6), 256, 0, stream>>>(Ae2, WeT, b_enc, pos, outb, 12608);
    k_head<<<64, 256, 0, stream>>>(outb, W_out, b_out, (float*)d_out);
}

// Round 5
// 403.533 us; speedup vs baseline: 4.0047x; 1.1654x over previous
//
#include <hip/hip_runtime.h>
#include <math.h>

#define SEQL 197
#define HD 768
#define NH 12
#define DHD 64
#define BATCH 64
#define OUTD 1000

typedef unsigned short ushort_t;
typedef __attribute__((ext_vector_type(8))) short bf16x8;
typedef __attribute__((ext_vector_type(4))) float f32x4;

static __device__ __forceinline__ unsigned short f2bf(float f) {
    union { float f; unsigned u; } v; v.f = f;
    unsigned r = v.u + 0x7fff + ((v.u >> 16) & 1);
    return (unsigned short)(r >> 16);
}

static __device__ __forceinline__ void gload16(const ushort_t* g, ushort_t* l) {
    __builtin_amdgcn_global_load_lds(
        (const __attribute__((address_space(1))) unsigned int*)g,
        (__attribute__((address_space(3))) unsigned int*)l, 16, 0, 0);
}

// ---------------- positional embedding table ----------------
__global__ void k_pos(float* __restrict__ pos) {
    int i = blockIdx.x * 256 + threadIdx.x;
    if (i >= SEQL * HD) return;
    int s = i / HD, d = i % HD;
    float f = (float)(d & ~1);
    float r = powf(10000.0f, -f / (float)HD);
    float a = (float)s * r;
    pos[i] = (d & 1) ? cosf(a) : sinf(a);
}

// ---------------- cls row of tokens ----------------
__global__ void k_cls(const float* __restrict__ cls_tok, const float* __restrict__ pos,
                      float* __restrict__ tok) {
    int i = blockIdx.x * 256 + threadIdx.x;
    if (i >= BATCH * HD) return;
    int b = i / HD, e = i % HD;
    tok[(b * SEQL) * HD + e] = cls_tok[e] + pos[e];
}

// ---------------- W (f32 [K][N]) -> W^T bf16 [N][K], K=N=768 ----------------
__global__ void k_cvtW(const float* __restrict__ W, ushort_t* __restrict__ WT) {
    int idx = blockIdx.x * 256 + threadIdx.x;       // 0 .. 768*192
    if (idx >= 768 * 192) return;
    int k = idx / 192, nq = idx % 192;
    float4 w = *(const float4*)&W[k * 768 + nq * 4];
    WT[(nq * 4 + 0) * 768 + k] = f2bf(w.x);
    WT[(nq * 4 + 1) * 768 + k] = f2bf(w.y);
    WT[(nq * 4 + 2) * 768 + k] = f2bf(w.z);
    WT[(nq * 4 + 3) * 768 + k] = f2bf(w.w);
}

// ---------------- Wq/Wk/Wv [12][64 d][64 e] f32 -> wt bf16 [3][12][64 e][64 d] ----
__global__ void k_cvtWqkv(const float* __restrict__ Wq, const float* __restrict__ Wk,
                          const float* __restrict__ Wv, ushort_t* __restrict__ wt) {
    int idx = blockIdx.x * 256 + threadIdx.x;       // over 3*12*64*16 = 36864
    if (idx >= 36864) return;
    int dq = idx & 15;
    int e  = (idx >> 4) & 63;
    int h  = (idx >> 10) % 12;
    int pj = idx / 12288;
    const float* W = (pj == 0) ? Wq : (pj == 1) ? Wk : Wv;
    ushort4 o;
    o.x = f2bf(W[(h * 64 + dq * 4 + 0) * 64 + e]);
    o.y = f2bf(W[(h * 64 + dq * 4 + 1) * 64 + e]);
    o.z = f2bf(W[(h * 64 + dq * 4 + 2) * 64 + e]);
    o.w = f2bf(W[(h * 64 + dq * 4 + 3) * 64 + e]);
    *(ushort4*)&wt[(size_t)((pj * 12 + h) * 64 + e) * 64 + dq * 4] = o;
}

// ---------------- gather patches -> bf16 A [12544][768] ----------------
__global__ void k_prep_patches(const float* __restrict__ img, ushort_t* __restrict__ Ae) {
    int idx = blockIdx.x * 256 + threadIdx.x;       // 0 .. 12544*192
    int m = idx / 192, kq = idx % 192;
    int k0 = kq * 4;
    int c = k0 >> 8, rem = k0 & 255, ir = rem >> 4, jc = rem & 15;
    int b = m / 196, pi = m % 196;
    int pr = pi / 14, pc = pi % 14;
    float4 v = *(const float4*)&img[((b * 3 + c) * 224 + pr * 16 + ir) * 224 + pc * 16 + jc];
    ushort4 o;
    o.x = f2bf(v.x); o.y = f2bf(v.y); o.z = f2bf(v.z); o.w = f2bf(v.w);
    *(ushort4*)&Ae[m * 768 + k0] = o;
}

// ---------------- bf16 MFMA GEMM, 128x128 tile, BK=64, 4 waves ----------------
template <int MODE>
__launch_bounds__(256)
__global__ void k_gemm_bf16(const ushort_t* __restrict__ A, const ushort_t* __restrict__ Bt,
                            const float* __restrict__ bias, const float* __restrict__ pos,
                            float* __restrict__ out, int Mtot) {
    __shared__ ushort_t As[128 * 64];
    __shared__ ushort_t Bs[128 * 64];
    const int m0 = blockIdx.x * 128;
    const int n0 = blockIdx.y * 128;
    const int tid = threadIdx.x;
    const int lane = tid & 63, wave = tid >> 6;
    const int wm = wave >> 1, wn = wave & 1;

    f32x4 acc[4][4];
#pragma unroll
    for (int i = 0; i < 4; ++i)
#pragma unroll
        for (int j = 0; j < 4; ++j)
#pragma unroll
            for (int r = 0; r < 4; ++r) acc[i][j][r] = 0.f;

    for (int kt = 0; kt < 12; ++kt) {
        const int k0 = kt * 64;
#pragma unroll
        for (int t = 0; t < 4; ++t) {
            int c = (wave << 2) | t;
            int o = c * 1024 + lane * 16;
            int row = o >> 7;
            int inner = o & 127;
            int col = (inner ^ ((row & 7) << 4)) >> 1;
            gload16(&A[(size_t)(m0 + row) * 768 + k0 + col], &As[c * 512]);
            gload16(&Bt[(size_t)(n0 + row) * 768 + k0 + col], &Bs[c * 512]);
        }
        __syncthreads();
#pragma unroll
        for (int ks = 0; ks < 2; ++ks) {
            const int cbyte = ks * 64 + (lane >> 4) * 16;
            bf16x8 af[4], bf[4];
#pragma unroll
            for (int mi = 0; mi < 4; ++mi) {
                int row = wm * 64 + mi * 16 + (lane & 15);
                af[mi] = *(const bf16x8*)((const char*)As + row * 128 + (cbyte ^ ((row & 7) << 4)));
            }
#pragma unroll
            for (int ni = 0; ni < 4; ++ni) {
                int n = wn * 64 + ni * 16 + (lane & 15);
                bf[ni] = *(const bf16x8*)((const char*)Bs + n * 128 + (cbyte ^ ((n & 7) << 4)));
            }
#pragma unroll
            for (int mi = 0; mi < 4; ++mi)
#pragma unroll
                for (int ni = 0; ni < 4; ++ni)
                    acc[mi][ni] = __builtin_amdgcn_mfma_f32_16x16x32_bf16(af[mi], bf[ni], acc[mi][ni], 0, 0, 0);
        }
        __syncthreads();
    }

    const int colb = n0 + wn * 64 + (lane & 15);
    const int rowb = m0 + wm * 64 + (lane >> 4) * 4;
#pragma unroll
    for (int ni = 0; ni < 4; ++ni) {
        const int n = colb + ni * 16;
        const float bn = bias[n];
#pragma unroll
        for (int mi = 0; mi < 4; ++mi) {
#pragma unroll
            for (int r = 0; r < 4; ++r) {
                int m = rowb + mi * 16 + r;
                if (MODE == 0) {
                    int b = m / 196, s = 1 + m % 196;
                    out[((b * SEQL) + s) * HD + n] = acc[mi][ni][r] + bn + pos[s * HD + n];
                } else {
                    if (m < Mtot) {
                        float* p = &out[(size_t)m * HD + n];
                        *p = *p + fmaxf(acc[mi][ni][r] + bn, 0.f);
                    }
                }
            }
        }
    }
}

// ---------------- 2D LayerNorm stats (mean, rsigma) per image ----------------
__global__ void k_lnstats(const float* __restrict__ buf, float* __restrict__ stats, int which) {
    int b = blockIdx.x;
    const float* p = buf + (size_t)b * SEQL * HD;
    float s = 0.f, s2 = 0.f;
    const int NV = SEQL * HD / 4;
    for (int i = threadIdx.x; i < NV; i += 256) {
        float4 v = ((const float4*)p)[i];
        s += v.x + v.y + v.z + v.w;
        s2 += v.x * v.x + v.y * v.y + v.z * v.z + v.w * v.w;
    }
    __shared__ float rs[8], rs2[8];
#pragma unroll
    for (int off = 32; off > 0; off >>= 1) {
        s += __shfl_down(s, off);
        s2 += __shfl_down(s2, off);
    }
    int lane = threadIdx.x & 63, w = threadIdx.x >> 6;
    if (lane == 0) { rs[w] = s; rs2[w] = s2; }
    __syncthreads();
    if (threadIdx.x == 0) {
        float S = 0.f, S2 = 0.f;
        for (int i = 0; i < 4; ++i) { S += rs[i]; S2 += rs2[i]; }
        const float inv_n = 1.0f / (float)(SEQL * HD);
        float mu = S * inv_n;
        float var = S2 * inv_n - mu * mu;
        stats[which * 128 + b * 2] = mu;
        stats[which * 128 + b * 2 + 1] = rsqrtf(var + 1e-5f);
    }
}

// ---------------- LN1 apply -> bf16 xb [12608][768] ----------------
__global__ void k_ln1(const float* __restrict__ tok, const float* __restrict__ stats,
                      const float* __restrict__ g1, const float* __restrict__ b1,
                      ushort_t* __restrict__ xb) {
    int i = blockIdx.x * 256 + threadIdx.x;
    if (i >= BATCH * SEQL * HD / 4) return;
    int e4 = i * 4;
    int m = e4 / HD, kk = e4 % HD;
    int b = m / SEQL, s = m % SEQL;
    float mu = stats[b * 2], rsg = stats[b * 2 + 1];
    float4 t = *(const float4*)&tok[e4];
    float4 g = *(const float4*)&g1[s * HD + kk];
    float4 bb = *(const float4*)&b1[s * HD + kk];
    ushort4 o;
    o.x = f2bf((t.x - mu) * rsg * g.x + bb.x);
    o.y = f2bf((t.y - mu) * rsg * g.y + bb.y);
    o.z = f2bf((t.z - mu) * rsg * g.z + bb.z);
    o.w = f2bf((t.w - mu) * rsg * g.w + bb.w);
    *(ushort4*)&xb[e4] = o;
}

// ---------------- MFMA QKV: per (half, h, b), 128 rows x 64 e x 3 proj ----------
// q,k out: bf16 [bh][256][64] (pad rows untouched). vt out: bf16 [bh][64][256].
__launch_bounds__(256)
__global__ void k_qkv_mfma(const ushort_t* __restrict__ xb, const ushort_t* __restrict__ wt,
                           const float* __restrict__ bq, const float* __restrict__ bk,
                           const float* __restrict__ bv,
                           ushort_t* __restrict__ q16, ushort_t* __restrict__ k16,
                           ushort_t* __restrict__ vt16) {
    const int half = blockIdx.x, h = blockIdx.y, b = blockIdx.z;
    __shared__ ushort_t Xs[128 * 64];   // swizzled X tile [128 s][64 d]
    __shared__ ushort_t Ob[128 * 72];   // bounce: Q/K [128][72]; V [64][132]
    const int tid = threadIdx.x;
    const int lane = tid & 63, wave = tid >> 6;
    const int l16 = lane & 15, l4 = lane >> 4;
    const int sbase = half * 128;

    // stage X tile (rows s_local 0..127, cols d 0..63 of head h)
    const size_t xrow0 = (size_t)b * SEQL + sbase;
#pragma unroll
    for (int t = 0; t < 4; ++t) {
        int c = (wave << 2) | t;
        int row = (c << 3) | (lane >> 3);
        int col = ((lane & 7) ^ (row & 7)) << 3;
        gload16(&xb[(xrow0 + row) * 768 + h * 64 + col], &Xs[c * 512]);
    }
    __syncthreads();

    // A fragments (live across all 3 projections)
    bf16x8 af[2][2];
#pragma unroll
    for (int mi = 0; mi < 2; ++mi)
#pragma unroll
        for (int kk = 0; kk < 2; ++kk) {
            int row = wave * 32 + mi * 16 + l16;
            af[mi][kk] = *(const bf16x8*)((const char*)Xs + row * 128 +
                                          ((kk * 64 + l4 * 16) ^ ((row & 7) << 4)));
        }

    for (int pj = 0; pj < 3; ++pj) {
        const float* bptr = (pj == 0) ? bq : (pj == 1) ? bk : bv;
        bf16x8 wf[4][2];
#pragma unroll
        for (int ni = 0; ni < 4; ++ni)
#pragma unroll
            for (int kk = 0; kk < 2; ++kk)
                wf[ni][kk] = *(const bf16x8*)&wt[(size_t)((pj * 12 + h) * 64 + ni * 16 + l16) * 64 + kk * 32 + l4 * 8];

        f32x4 acc[2][4];
#pragma unroll
        for (int mi = 0; mi < 2; ++mi)
#pragma unroll
            for (int ni = 0; ni < 4; ++ni) {
                acc[mi][ni][0] = 0.f; acc[mi][ni][1] = 0.f;
                acc[mi][ni][2] = 0.f; acc[mi][ni][3] = 0.f;
            }
#pragma unroll
        for (int mi = 0; mi < 2; ++mi)
#pragma unroll
            for (int ni = 0; ni < 4; ++ni) {
                acc[mi][ni] = __builtin_amdgcn_mfma_f32_16x16x32_bf16(af[mi][0], wf[ni][0], acc[mi][ni], 0, 0, 0);
                acc[mi][ni] = __builtin_amdgcn_mfma_f32_16x16x32_bf16(af[mi][1], wf[ni][1], acc[mi][ni], 0, 0, 0);
            }

        float bias4[4];
#pragma unroll
        for (int ni = 0; ni < 4; ++ni) bias4[ni] = bptr[h * 64 + ni * 16 + l16];

        if (pj < 2) {
            // C layout: col e = lane&15, row s_local = (lane>>4)*4 + r
#pragma unroll
            for (int mi = 0; mi < 2; ++mi)
#pragma unroll
                for (int ni = 0; ni < 4; ++ni)
#pragma unroll
                    for (int r = 0; r < 4; ++r) {
                        int sl = wave * 32 + mi * 16 + l4 * 4 + r;
                        Ob[sl * 72 + ni * 16 + l16] = f2bf(acc[mi][ni][r] + bias4[ni]);
                    }
            __syncthreads();
            ushort_t* dst = (pj == 0) ? q16 : k16;
            const size_t qkb = (size_t)(b * 12 + h) * 256 * 64;
            int row = tid >> 1, hw = tid & 1;
            int s = sbase + row;
            if (s < SEQL) {
#pragma unroll
                for (int i = 0; i < 4; ++i)
                    *(uint4*)&dst[qkb + (size_t)s * 64 + hw * 32 + i * 8] =
                        *(const uint4*)&Ob[row * 72 + hw * 32 + i * 8];
            }
            __syncthreads();
        } else {
            // V: store transposed into Ob [64 e][132 sl]
#pragma unroll
            for (int mi = 0; mi < 2; ++mi)
#pragma unroll
                for (int ni = 0; ni < 4; ++ni)
#pragma unroll
                    for (int r = 0; r < 4; ++r) {
                        int sl = wave * 32 + mi * 16 + l4 * 4 + r;
                        Ob[(ni * 16 + l16) * 132 + sl] = f2bf(acc[mi][ni][r] + bias4[ni]);
                    }
            __syncthreads();
            const size_t vbase = (size_t)(b * 12 + h) * 64 * 256;
            int e = tid >> 2, qq = tid & 3;
#pragma unroll
            for (int i = 0; i < 8; ++i) {
                int s = sbase + qq * 32 + i * 4;
                if (s < SEQL)
                    *(uint2*)&vt16[vbase + (size_t)e * 256 + s] =
                        *(const uint2*)&Ob[e * 132 + qq * 32 + i * 4];
            }
        }
    }
}

// ---------------- MFMA flash attention + residual ----------------
__launch_bounds__(512)
__global__ void k_attn_mfma(const ushort_t* __restrict__ q, const ushort_t* __restrict__ k,
                            const ushort_t* __restrict__ vt, const float* __restrict__ tok,
                            float* __restrict__ out) {
    const int h = blockIdx.x, b = blockIdx.y;
    const int tid = threadIdx.x;
    const int wave = tid >> 6, lane = tid & 63;
    const int l16 = lane & 15, l4 = lane >> 4;
    __shared__ ushort_t Ps[8][32 * 72];

    const size_t qkbase = (size_t)(b * 12 + h) * 256 * 64;
    const size_t vbase  = (size_t)(b * 12 + h) * 64 * 256;
    const int r0 = wave * 32;

    bf16x8 qa[2][2];
#pragma unroll
    for (int mi = 0; mi < 2; ++mi)
#pragma unroll
        for (int kk = 0; kk < 2; ++kk)
            qa[mi][kk] = *(const bf16x8*)&q[qkbase + (size_t)(r0 + mi * 16 + l16) * 64 + kk * 32 + l4 * 8];

    f32x4 oacc[2][4];
    float m_s[2][4], l_s[2][4];
#pragma unroll
    for (int mi = 0; mi < 2; ++mi) {
#pragma unroll
        for (int r = 0; r < 4; ++r) {
            m_s[mi][r] = -INFINITY;
            l_s[mi][r] = 0.f;
        }
#pragma unroll
        for (int ne = 0; ne < 4; ++ne)
#pragma unroll
            for (int r = 0; r < 4; ++r) oacc[mi][ne][r] = 0.f;
    }

    ushort_t* myP = &Ps[wave][0];

    for (int tt = 0; tt < 4; ++tt) {
        const int t0 = tt * 64;
        bf16x8 kf[4][2];
#pragma unroll
        for (int ni = 0; ni < 4; ++ni)
#pragma unroll
            for (int kk = 0; kk < 2; ++kk)
                kf[ni][kk] = *(const bf16x8*)&k[qkbase + (size_t)(t0 + ni * 16 + l16) * 64 + kk * 32 + l4 * 8];

        f32x4 sa[2][4];
#pragma unroll
        for (int mi = 0; mi < 2; ++mi)
#pragma unroll
            for (int ni = 0; ni < 4; ++ni) {
                f32x4 z;
                z[0] = 0.f; z[1] = 0.f; z[2] = 0.f; z[3] = 0.f;
                z = __builtin_amdgcn_mfma_f32_16x16x32_bf16(qa[mi][0], kf[ni][0], z, 0, 0, 0);
                sa[mi][ni] = __builtin_amdgcn_mfma_f32_16x16x32_bf16(qa[mi][1], kf[ni][1], z, 0, 0, 0);
            }

#pragma unroll
        for (int mi = 0; mi < 2; ++mi) {
#pragma unroll
            for (int r = 0; r < 4; ++r) {
                float sv[4];
                float mt = -INFINITY;
#pragma unroll
                for (int ni = 0; ni < 4; ++ni) {
                    float s = sa[mi][ni][r] * 0.125f;
                    if (t0 + ni * 16 + l16 >= SEQL) s = -1e30f;
                    sv[ni] = s;
                    mt = fmaxf(mt, s);
                }
                mt = fmaxf(mt, __shfl_xor(mt, 1));
                mt = fmaxf(mt, __shfl_xor(mt, 2));
                mt = fmaxf(mt, __shfl_xor(mt, 4));
                mt = fmaxf(mt, __shfl_xor(mt, 8));
                float mn = fmaxf(m_s[mi][r], mt);
                float alpha = __expf(m_s[mi][r] - mn);
                m_s[mi][r] = mn;
                float rsum = 0.f;
#pragma unroll
                for (int ni = 0; ni < 4; ++ni) {
                    float p = __expf(sv[ni] - mn);
                    rsum += p;
                    myP[(mi * 16 + l4 * 4 + r) * 72 + ni * 16 + l16] = f2bf(p);
                }
                rsum += __shfl_xor(rsum, 1);
                rsum += __shfl_xor(rsum, 2);
                rsum += __shfl_xor(rsum, 4);
                rsum += __shfl_xor(rsum, 8);
                l_s[mi][r] = l_s[mi][r] * alpha + rsum;
#pragma unroll
                for (int ne = 0; ne < 4; ++ne) oacc[mi][ne][r] *= alpha;
            }
        }

        bf16x8 vf[4][2];
#pragma unroll
        for (int ne = 0; ne < 4; ++ne)
#pragma unroll
            for (int kk = 0; kk < 2; ++kk)
                vf[ne][kk] = *(const bf16x8*)&vt[vbase + (size_t)(ne * 16 + l16) * 256 + t0 + kk * 32 + l4 * 8];
        bf16x8 pa[2][2];
#pragma unroll
        for (int mi = 0; mi < 2; ++mi)
#pragma unroll
            for (int kk = 0; kk < 2; ++kk)
                pa[mi][kk] = *(const bf16x8*)&myP[(mi * 16 + l16) * 72 + kk * 32 + l4 * 8];
#pragma unroll
        for (int mi = 0; mi < 2; ++mi)
#pragma unroll
            for (int ne = 0; ne < 4; ++ne) {
                oacc[mi][ne] = __builtin_amdgcn_mfma_f32_16x16x32_bf16(pa[mi][0], vf[ne][0], oacc[mi][ne], 0, 0, 0);
                oacc[mi][ne] = __builtin_amdgcn_mfma_f32_16x16x32_bf16(pa[mi][1], vf[ne][1], oacc[mi][ne], 0, 0, 0);
            }
    }

#pragma unroll
    for (int mi = 0; mi < 2; ++mi) {
#pragma unroll
        for (int r = 0; r < 4; ++r) {
            int row = r0 + mi * 16 + l4 * 4 + r;
            if (row < SEQL) {
                float inv = 1.0f / l_s[mi][r];
                size_t off = ((size_t)(b * SEQL + row)) * HD + h * 64;
#pragma unroll
                for (int ne = 0; ne < 4; ++ne) {
                    int e = ne * 16 + l16;
                    out[off + e] = oacc[mi][ne][r] * inv + tok[off + e];
                }
            }
        }
    }
}

// ---------------- LN2 apply -> bf16 A for encoder GEMM ----------------
__global__ void k_ln2apply(const float* __restrict__ outb, const float* __restrict__ stats,
                           const float* __restrict__ g2, const float* __restrict__ b2,
                           ushort_t* __restrict__ x) {
    int i = blockIdx.x * 256 + threadIdx.x;
    if (i >= BATCH * SEQL * HD / 4) return;
    int e4 = i * 4;
    int m = e4 / HD, kk = e4 % HD;
    int b = m / SEQL, s = m % SEQL;
    float mu = stats[128 + b * 2], rsg = stats[128 + b * 2 + 1];
    float4 t = *(const float4*)&outb[e4];
    float4 g = *(const float4*)&g2[s * HD + kk];
    float4 bb = *(const float4*)&b2[s * HD + kk];
    ushort4 o;
    o.x = f2bf((t.x - mu) * rsg * g.x + bb.x);
    o.y = f2bf((t.y - mu) * rsg * g.y + bb.y);
    o.z = f2bf((t.z - mu) * rsg * g.z + bb.z);
    o.w = f2bf((t.w - mu) * rsg * g.w + bb.w);
    *(ushort4*)&x[e4] = o;
}

// ---------------- classifier head + softmax ----------------
__launch_bounds__(256)
__global__ void k_head(const float* __restrict__ out, const float* __restrict__ Wo,
                       const float* __restrict__ bo, float* __restrict__ dout) {
    const int b = blockIdx.x, tid = threadIdx.x;
    __shared__ float cls[768];
    __shared__ float red[256];
    for (int i = tid; i < 192; i += 256)
        *(float4*)&cls[i * 4] = *(const float4*)&out[(b * SEQL) * HD + i * 4];
    __syncthreads();

    const int o0 = tid * 4;
    const bool ok = (o0 < OUTD);
    float4 acc = {0.f, 0.f, 0.f, 0.f};
    if (ok) {
        acc = *(const float4*)&bo[o0];
        for (int e = 0; e < 768; ++e) {
            float c = cls[e];
            float4 w = *(const float4*)&Wo[e * OUTD + o0];
            acc.x += c * w.x;
            acc.y += c * w.y;
            acc.z += c * w.z;
            acc.w += c * w.w;
        }
    }
    float mx = ok ? fmaxf(fmaxf(acc.x, acc.y), fmaxf(acc.z, acc.w)) : -INFINITY;
    red[tid] = mx;
    __syncthreads();
    for (int s = 128; s > 0; s >>= 1) {
        if (tid < s) red[tid] = fmaxf(red[tid], red[tid + s]);
        __syncthreads();
    }
    float M = red[0];
    __syncthreads();
    float4 p = {0.f, 0.f, 0.f, 0.f};
    float ls = 0.f;
    if (ok) {
        p.x = expf(acc.x - M);
        p.y = expf(acc.y - M);
        p.z = expf(acc.z - M);
        p.w = expf(acc.w - M);
        ls = p.x + p.y + p.z + p.w;
    }
    red[tid] = ls;
    __syncthreads();
    for (int s = 128; s > 0; s >>= 1) {
        if (tid < s) red[tid] += red[tid + s];
        __syncthreads();
    }
    float inv = 1.0f / red[0];
    if (ok) {
        p.x *= inv; p.y *= inv; p.z *= inv; p.w *= inv;
        *(float4*)&dout[b * OUTD + o0] = p;
    }
}

extern "C" void kernel_launch(void* const* d_in, const int* in_sizes, int n_in,
                              void* d_out, int out_size, void* d_ws, size_t ws_size,
                              hipStream_t stream) {
    const float* images  = (const float*)d_in[0];
    const float* W_map   = (const float*)d_in[1];
    const float* b_map   = (const float*)d_in[2];
    const float* cls_tok = (const float*)d_in[3];
    const float* ln1_g   = (const float*)d_in[4];
    const float* ln1_b   = (const float*)d_in[5];
    const float* Wq      = (const float*)d_in[6];
    const float* bq      = (const float*)d_in[7];
    const float* Wk      = (const float*)d_in[8];
    const float* bk      = (const float*)d_in[9];
    const float* Wv      = (const float*)d_in[10];
    const float* bv      = (const float*)d_in[11];
    const float* ln2_g   = (const float*)d_in[12];
    const float* ln2_b   = (const float*)d_in[13];
    const float* W_enc   = (const float*)d_in[14];
    const float* b_enc   = (const float*)d_in[15];
    const float* W_out   = (const float*)d_in[16];
    const float* b_out   = (const float*)d_in[17];

    float* ws = (float*)d_ws;
    const size_t BIG = (size_t)BATCH * SEQL * HD;     // 9,682,944
    const size_t QKB = (size_t)BATCH * 12 * 256 * 64; // 12,582,912 u16 per buffer

    float* pos   = ws;
    float* tok   = ws + 151552;
    float* outb  = tok + BIG;
    float* stats = outb + BIG;
    ushort_t* q16  = (ushort_t*)(stats + 256);
    ushort_t* k16  = q16 + QKB;
    ushort_t* vt16 = k16 + QKB;
    ushort_t* xb   = vt16 + QKB;                      // bf16 [12672][768] (pad rows unwritten)
    ushort_t* wtq  = xb + (size_t)12672 * 768;        // bf16 [3][12][64][64]

    // overlays (regions dead at time of use):
    ushort_t* Ae  = q16;                              // patches bf16 (dead before k_qkv_mfma)
    ushort_t* WmT = k16;                              // W_map^T bf16
    ushort_t* Ae2 = q16;                              // LN2-out bf16 (q16 dead after attn)
    ushort_t* WeT = k16;                              // W_enc^T bf16 (k16 dead after attn)

    k_pos<<<591, 256, 0, stream>>>(pos);
    k_cls<<<192, 256, 0, stream>>>(cls_tok, pos, tok);
    k_cvtW<<<576, 256, 0, stream>>>(W_map, WmT);
    k_prep_patches<<<9408, 256, 0, stream>>>(images, Ae);
    k_gemm_bf16<0><<<dim3(98, 6), 256, 0, stream>>>(Ae, WmT, b_map, pos, tok, 12544);
    k_lnstats<<<64, 256, 0, stream>>>(tok, stats, 0);
    k_ln1<<<9456, 256, 0, stream>>>(tok, stats, ln1_g, ln1_b, xb);
    k_cvtWqkv<<<144, 256, 0, stream>>>(Wq, Wk, Wv, wtq);
    k_qkv_mfma<<<dim3(2, 12, 64), 256, 0, stream>>>(xb, wtq, bq, bk, bv, q16, k16, vt16);
    k_attn_mfma<<<dim3(12, 64), 512, 0, stream>>>(q16, k16, vt16, tok, outb);
    k_cvtW<<<576, 256, 0, stream>>>(W_enc, WeT);
    k_lnstats<<<64, 256, 0, stream>>>(outb, stats, 1);
    k_ln2apply<<<9456, 256, 0, stream>>>(outb, stats, ln2_g, ln2_b, Ae2);
    k_gemm_bf16<1><<<dim3(99, 6), 256, 0, stream>>>(Ae2, WeT, b_enc, pos, outb, 12608);
    k_head<<<64, 256, 0, stream>>>(outb, W_out, b_out, (float*)d_out);
}